// Round 10
// baseline (691.935 us; speedup 1.0000x reference)
//
#include <hip/hip_runtime.h>

// GATCL: 2-head GAT (N=8192, D=256) + feature conv (K=129) + GAT(D=128) + 2 MLPs + pair dots.
// R12: agg_head reverted to R9/R8 (best measured). Independent work fused into single
// launches for intra-launch overlap (graph capture forbids multi-stream):
//   k_prep      = cast_x | wt          (independent)
//   k_gemm_pack = gemm_h | pack        (pack fills CU slots gemm's 512-block grid leaves idle)
//   k_post      = gmax | colterms      (one wh2 pass)
// agg_conv / agg_head / rest unchanged from R9.

typedef _Float16 f16;
typedef _Float16 f16x8 __attribute__((ext_vector_type(8)));
typedef float f32x4 __attribute__((ext_vector_type(4)));

#define DEV __device__ __forceinline__
#define L2E 1.4426950408889634f
#define NN 8192
#define IND 768
#define D1 256
#define DT 512
#define D2 128
#define KC 129
#define EPAIRS 100000
#define JS1 4

#if __has_builtin(__builtin_amdgcn_exp2f)
#define EXP2(x) __builtin_amdgcn_exp2f(x)
#else
#define EXP2(x) exp2f(x)
#endif

DEV float eluf(float x){ return x > 0.f ? x : EXP2(x*L2E) - 1.f; }

// async 16B global->LDS (LDS dest is wave-uniform base; lane writes base+lane*16)
DEV void gload_lds16(const void* g, void* l){
  __builtin_amdgcn_global_load_lds(
      (const __attribute__((address_space(1))) unsigned*)g,
      (__attribute__((address_space(3))) unsigned*)l, 16, 0, 0);
}

// ---------------- P: cast x to fp16 | W' transpose+cast (independent, fused) ----------------
__global__ __launch_bounds__(256) void k_prep(
    const float* __restrict__ x, f16* __restrict__ x16,
    const float* __restrict__ W, f16* __restrict__ Wt){
  int b = blockIdx.x;
  if (b < DT){                       // wt part: Wt[n'=h*256+d][k] = W[h][k][d]
    int h = b >> 8, d = b & 255;
    for (int k = threadIdx.x; k < IND; k += 256)
      Wt[(size_t)b*IND + k] = (f16)W[((size_t)h*IND + k)*D1 + d];
  } else {                           // cast part
    int i = ((b - DT)*256 + threadIdx.x)*4;
    float4 v = *(const float4*)(x + i);
    union { f16 h[4]; uint2 u; } p;
    p.h[0]=(f16)v.x; p.h[1]=(f16)v.y; p.h[2]=(f16)v.z; p.h[3]=(f16)v.w;
    *(uint2*)(x16 + i) = p.u;
  }
}

// ---------------- G1|P0: h = x @ W' (blocks 0..511) | adjacency bit-pack (blocks 512..) ----------------
// gemm: R9 body — gload_lds16 staging, As/Bs linear + chunk-XOR swizzle, (256,4).
// pack blocks fill CU slots the 512-block gemm grid leaves idle (overlap HBM vs MFMA).
__global__ __launch_bounds__(256, 4) void k_gemm_pack(
    const f16* __restrict__ x16, const f16* __restrict__ Wt,
    const float* __restrict__ head_a,
    f16* __restrict__ hT, float* __restrict__ wh1, float* __restrict__ wh2,
    const int4* __restrict__ adj4, unsigned* __restrict__ maskw){
  __shared__ f16 As[64*64];      // linear, 16B-chunk swizzled within each 128B row
  __shared__ f16 Bs[128*64];     // linear, 16B-chunk swizzled
  int blk = blockIdx.x;
  if (blk >= 512){
    // ---- pack: int32 0/1 -> bit mask, int4 loads ----
    int idx = (blk - 512)*256 + threadIdx.x;       // int4 index; j-flat = 4*idx
    int4 v = adj4[idx];
    unsigned n = (unsigned)(v.x > 0) | ((unsigned)(v.y > 0) << 1)
               | ((unsigned)(v.z > 0) << 2) | ((unsigned)(v.w > 0) << 3);
    n |= __shfl_xor(n, 1) << 4;
    n |= __shfl_xor(n, 2) << 8;
    n |= __shfl_xor(n, 4) << 16;
    if ((threadIdx.x & 7) == 0) maskw[idx >> 3] = n;
    return;
  }
  // ---- gemm: m0 = bx*64, n0 = by*128 ----
  int m0 = (blk & 127)*64, n0 = (blk >> 7)*128;
  int t = threadIdx.x, lane = t & 63, w = t >> 6;
  int wi = w >> 1, wd = w & 1;
  int rm = lane & 15, qm = (lane >> 4)*8;
  const int wb = t & ~63;        // wave-uniform staging base index
  f32x4 acc[2][4] = {};
  for (int k0 = 0; k0 < IND; k0 += 64){
#pragma unroll
    for (int p = 0; p < 2; p++){
      int idx = p*256 + t;
      int dr = idx >> 3, gch = (idx & 7) ^ (dr & 7);
      gload_lds16(&x16[(size_t)(m0 + dr)*IND + k0 + gch*8], &As[(p*256 + wb)*8]);
    }
#pragma unroll
    for (int p = 0; p < 4; p++){
      int idx = p*256 + t;
      int dr = idx >> 3, gch = (idx & 7) ^ (dr & 7);
      gload_lds16(&Wt[(size_t)(n0 + dr)*IND + k0 + gch*8], &Bs[(p*256 + wb)*8]);
    }
    __syncthreads();
#pragma unroll
    for (int ks = 0; ks < 2; ks++){
      int sc = (ks*4 + (qm >> 3)) ^ (rm & 7);  // swizzled 16B-chunk within row
      f16x8 a0 = *(const f16x8*)&As[(wi*32 + rm)*64 + sc*8];
      f16x8 a1 = *(const f16x8*)&As[(wi*32 + 16 + rm)*64 + sc*8];
#pragma unroll
      for (int fn = 0; fn < 4; fn++){
        f16x8 b = *(const f16x8*)&Bs[(wd*64 + fn*16 + rm)*64 + sc*8];
        acc[0][fn] = __builtin_amdgcn_mfma_f32_16x16x32_f16(a0, b, acc[0][fn], 0, 0, 0);
        acc[1][fn] = __builtin_amdgcn_mfma_f32_16x16x32_f16(a1, b, acc[1][fn], 0, 0, 0);
      }
    }
    __syncthreads();
  }
  int quad = lane >> 4, cl = lane & 15;
  int head = n0 >> 8;
  float a1v[4], a2v[4];
#pragma unroll
  for (int fn = 0; fn < 4; fn++){
    int d = (n0 & 255) + wd*64 + fn*16 + cl;
    a1v[fn] = head_a[head*DT + d];
    a2v[fn] = head_a[head*DT + D1 + d];
  }
  float p1[2][4], p2[2][4];
#pragma unroll
  for (int fi = 0; fi < 2; fi++){
#pragma unroll
    for (int fn = 0; fn < 4; fn++){
      int npg = n0 + wd*64 + fn*16 + cl;
      int mg = m0 + wi*32 + fi*16 + quad*4;
      union { f16 h[4]; uint2 u; } pk;
#pragma unroll
      for (int reg = 0; reg < 4; reg++) pk.h[reg] = (f16)acc[fi][fn][reg];
      *(uint2*)&hT[(size_t)npg*NN + mg] = pk.u;
    }
#pragma unroll
    for (int reg = 0; reg < 4; reg++){
      float s1 = 0.f, s2 = 0.f;
#pragma unroll
      for (int fn = 0; fn < 4; fn++){ s1 += acc[fi][fn][reg]*a1v[fn]; s2 += acc[fi][fn][reg]*a2v[fn]; }
      p1[fi][reg] = s1; p2[fi][reg] = s2;
    }
  }
#pragma unroll
  for (int o = 1; o < 16; o <<= 1){
#pragma unroll
    for (int fi = 0; fi < 2; fi++)
#pragma unroll
      for (int reg = 0; reg < 4; reg++){
        p1[fi][reg] += __shfl_xor(p1[fi][reg], o);
        p2[fi][reg] += __shfl_xor(p2[fi][reg], o);
      }
  }
  if (cl == 0){
#pragma unroll
    for (int fi = 0; fi < 2; fi++)
#pragma unroll
      for (int reg = 0; reg < 4; reg++){
        int mg = m0 + wi*32 + fi*16 + quad*4 + reg;
        atomicAdd(&wh1[head*NN + mg], p1[fi][reg]);
        atomicAdd(&wh2[head*NN + mg], p2[fi][reg]);
      }
  }
}

// ---------------- P4: gmax | colterms fused (one wh2 pass) ----------------
__global__ __launch_bounds__(256) void k_post(const float* __restrict__ wh2,
                                              unsigned* __restrict__ gmax,
                                              float* __restrict__ c1){
  int i = blockIdx.x*256 + threadIdx.x;    // over 2*NN; waves never straddle heads
  float v = wh2[i];
  c1[i] = v*L2E;
  int h = i >> 13;                          // i / NN
  float m = v;
#pragma unroll
  for (int o = 32; o > 0; o >>= 1) m = fmaxf(m, __shfl_xor(m, o));
  if ((threadIdx.x & 63) == 0){
    unsigned b = __float_as_uint(m);
    unsigned enc = (b & 0x80000000u) ? ~b : (b | 0x80000000u);
    atomicMax(gmax + h, enc);
  }
}

// ---------------- A1: head GAT aggregation. i-tile 64, full D=256, j-split 4 ----------------
// R8/R9 (best measured): LDS 40960 B, row terms in regs, c2 folded into FMA, 4 blocks/CU.
__global__ __launch_bounds__(256, 4) void k_agg_head(
    const f16* __restrict__ hT, const unsigned* __restrict__ maskw,
    const float* __restrict__ wh1, const float* __restrict__ c1,
    const unsigned* __restrict__ gmaxp,
    float* __restrict__ num, float* __restrict__ den){
  __shared__ f16 Hs[256*64];     // linear, 16B-chunk swizzled within each 128B row
  __shared__ f16 Ws[64*64];      // linear, 16B-chunk swizzled
  int head = blockIdx.z;
  int i0 = blockIdx.x*64;
  int jbase = blockIdx.y*(NN/JS1);
  const f16* hTh = hT + (size_t)head*D1*NN;
  int t = threadIdx.x, lane = t & 63, w = t >> 6;
  int rm = lane & 15, qm = (lane >> 4)*8;
  int si = t >> 2, sjq = (t & 3)*16;
  // per-row score terms (4 lanes per row; broadcast loads)
  unsigned e = gmaxp[head];
  float gmax = __uint_as_float((e & 0x80000000u) ? (e ^ 0x80000000u) : ~e);
  float u = wh1[head*NN + i0 + si];
  float sm = u + gmax;
  float M = (sm > 0.f ? sm : 0.2f*sm)*L2E;   // leaky(wh1+gmax) in log2 units
  float ra = u*L2E - M;                      // s1 = ra + c1[j]
  float rb = -0.8f*M;                        // s2 = 0.2*s1 + rb  (exact identity)
  const float* c1h = c1 + head*NN;
  const unsigned* mrowp = maskw + (size_t)(i0 + si)*(NN/32);
  float rden = 0.f;
  f32x4 acc[4][4] = {};
  const int wb = t & ~63;        // wave-uniform staging base index
  const int wsbase = si*64;
  const int wc0 = sjq >> 3;      // this thread's first 16B chunk in its Ws row
  for (int j0 = 0; j0 < NN/JS1; j0 += 64){
    int jg = jbase + j0;
    // stage Hs[d=256][j=64] via async DMA; per-lane global src picks chunk (c^(row&7))
#pragma unroll
    for (int p = 0; p < 8; p++){
      int idx = p*256 + t;
      int dr = idx >> 3, gch = (idx & 7) ^ (dr & 7);
      gload_lds16(hTh + (size_t)dr*NN + jg + gch*8, &Hs[(p*256 + wb)*8]);
    }
    // scores: streamed float4 reads (cache-resident), short live ranges
    unsigned mb = mrowp[(jg + sjq) >> 5] >> (sjq & 31);
    f16x8 wlo, whi;
    float dsum = 0.f;
#pragma unroll
    for (int k = 0; k < 4; k++){
      float4 va = *(const float4*)&c1h[jg + sjq + 4*k];
      float s0 = ra + va.x, s1 = ra + va.y, s2 = ra + va.z, s3 = ra + va.w;
      float w0 = EXP2(fmaxf(s0, fmaf(0.2f, s0, rb)));
      float w1 = EXP2(fmaxf(s1, fmaf(0.2f, s1, rb)));
      float w2 = EXP2(fmaxf(s2, fmaf(0.2f, s2, rb)));
      float w3 = EXP2(fmaxf(s3, fmaf(0.2f, s3, rb)));
      w0 = ((mb >> (4*k + 0)) & 1u) ? w0 : 0.f;
      w1 = ((mb >> (4*k + 1)) & 1u) ? w1 : 0.f;
      w2 = ((mb >> (4*k + 2)) & 1u) ? w2 : 0.f;
      w3 = ((mb >> (4*k + 3)) & 1u) ? w3 : 0.f;
      dsum += (w0 + w1) + (w2 + w3);
      if (k < 2){
        wlo[4*k]=(f16)w0; wlo[4*k+1]=(f16)w1; wlo[4*k+2]=(f16)w2; wlo[4*k+3]=(f16)w3;
      } else {
        whi[4*k-8]=(f16)w0; whi[4*k-7]=(f16)w1; whi[4*k-6]=(f16)w2; whi[4*k-5]=(f16)w3;
      }
    }
    *(f16x8*)&Ws[wsbase + ((wc0    ) ^ (si & 7))*8] = wlo;
    *(f16x8*)&Ws[wsbase + ((wc0 + 1) ^ (si & 7))*8] = whi;
    dsum += __shfl_xor(dsum, 1);
    dsum += __shfl_xor(dsum, 2);
    rden += dsum;
    __syncthreads();               // drains DMA (vmcnt) + Ws writes (lgkm)
    // MFMA: wave w owns d-range w*64..w*64+63, all 64 i
#pragma unroll
    for (int ks = 0; ks < 2; ks++){
      int sc = (ks*4 + (qm >> 3)) ^ (rm & 7);  // swizzled 16B-chunk within row
      f16x8 a[4], b[4];
#pragma unroll
      for (int mi = 0; mi < 4; mi++) a[mi] = *(const f16x8*)&Ws[(mi*16 + rm)*64 + sc*8];
#pragma unroll
      for (int fn = 0; fn < 4; fn++)
        b[fn] = *(const f16x8*)&Hs[(w*64 + fn*16 + rm)*64 + sc*8];
#pragma unroll
      for (int mi = 0; mi < 4; mi++)
#pragma unroll
        for (int fn = 0; fn < 4; fn++)
          acc[mi][fn] = __builtin_amdgcn_mfma_f32_16x16x32_f16(a[mi], b[fn], acc[mi][fn], 0, 0, 0);
    }
    __syncthreads();
  }
  if ((t & 3) == 0) atomicAdd(&den[head*NN + i0 + si], rden);
  int quad = lane >> 4, cl = lane & 15;
#pragma unroll
  for (int mi = 0; mi < 4; mi++)
#pragma unroll
    for (int fn = 0; fn < 4; fn++){
      int rr = i0 + mi*16 + quad*4;
      int dc = w*64 + fn*16 + cl;
#pragma unroll
      for (int reg = 0; reg < 4; reg++)
        atomicAdd(&num[((size_t)head*NN + rr + reg)*D1 + dc], acc[mi][fn][reg]);
    }
}

// ---------------- E1: merge heads -> z -> conv -> gT(fp16) + wc1L/wc2L ----------------
__global__ __launch_bounds__(256) void k_merge_conv(
    const float* __restrict__ num, const float* __restrict__ den,
    const float* __restrict__ head_b, const float* __restrict__ conv_w,
    const float* __restrict__ conv_cb, const float* __restrict__ conv_a,
    f16* __restrict__ gT, float* __restrict__ wc1L, float* __restrict__ wc2L){
  __shared__ float zrow[2][256];
  __shared__ float cw[KC];
  __shared__ float ca[256];
  __shared__ float red[2][2];
  __shared__ float red2[2][2][2];
  int t = threadIdx.x, g = t >> 7, c = t & 127;
  int r = blockIdx.x*2 + g;
  if (t < KC) cw[t] = conv_w[t];
  ca[t] = conv_a[t];
  float zv0 = 0.f, zv1 = 0.f;
#pragma unroll
  for (int h = 0; h < 2; h++){
    const float* nr = num + ((size_t)h*NN + r)*D1;
    float inv = 1.f / den[h*NN + r];
    float e0 = eluf(nr[c]*inv);
    float e1 = eluf(nr[c + 128]*inv);
    float ss = e0*e0 + e1*e1;
#pragma unroll
    for (int o = 32; o > 0; o >>= 1) ss += __shfl_xor(ss, o);
    if ((t & 63) == 0) red[g][(t >> 6) & 1] = ss;
    __syncthreads();
    float invn = 1.f / fmaxf(sqrtf(red[g][0] + red[g][1]), 1e-12f);
    zv0 += e0*invn + head_b[h*D1 + c];
    zv1 += e1*invn + head_b[h*D1 + 128 + c];
    __syncthreads();
  }
  zrow[g][c]       = eluf(0.5f*zv0);
  zrow[g][c + 128] = eluf(0.5f*zv1);
  __syncthreads();
  float s = conv_cb[0];
  for (int k = 0; k < KC; k++) s += zrow[g][c + k]*cw[k];
  gT[(size_t)c*NN + r] = (f16)s;
  float p1 = s*ca[c], p2 = s*ca[128 + c];
#pragma unroll
  for (int o = 32; o > 0; o >>= 1){ p1 += __shfl_xor(p1, o); p2 += __shfl_xor(p2, o); }
  if ((t & 63) == 0){ red2[g][(t >> 6) & 1][0] = p1; red2[g][(t >> 6) & 1][1] = p2; }
  __syncthreads();
  if ((t & 127) == 0){
    wc1L[r] = (red2[g][0][0] + red2[g][1][0])*L2E;
    wc2L[r] = (red2[g][0][1] + red2[g][1][1])*L2E;
  }
}

// ---------------- A2: conv GAT aggregation (elu scores, m=0). i-tile 64, D=128, j-split 8 ----------------
// R9 (unchanged): Ws linear-64 + chunk-XOR swizzle, rowc in regs, streamed scores. LDS 24576, (256,4).
__global__ __launch_bounds__(256, 4) void k_agg_conv(
    const f16* __restrict__ gT, const unsigned* __restrict__ maskw,
    const float* __restrict__ wc1L, const float* __restrict__ wc2L,
    float* __restrict__ num, float* __restrict__ den){
  __shared__ f16 Hs[128*64];     // linear, chunk-swizzled
  __shared__ f16 Ws[64*64];      // linear, chunk-swizzled
  int i0 = blockIdx.x*64;
  int jbase = blockIdx.y*1024;
  int t = threadIdx.x, lane = t & 63, w = t >> 6;
  int rm = lane & 15, qm = (lane >> 4)*8;
  int si = t >> 2, sjq = (t & 3)*16;
  float ra = wc1L[i0 + si];
  const unsigned* mrowp = maskw + (size_t)(i0 + si)*(NN/32);
  float rden = 0.f;
  f32x4 acc[4][2] = {};
  const int wb = t & ~63;
  const int wsbase = si*64;
  const int wc0 = sjq >> 3;
  for (int j0 = 0; j0 < 1024; j0 += 64){
    int jg = jbase + j0;
#pragma unroll
    for (int p = 0; p < 4; p++){
      int idx = p*256 + t;
      int dr = idx >> 3, gch = (idx & 7) ^ (dr & 7);
      gload_lds16(gT + (size_t)dr*NN + jg + gch*8, &Hs[(p*256 + wb)*8]);
    }
    unsigned mb = mrowp[(jg + sjq) >> 5] >> (sjq & 31);
    f16x8 wlo, whi;
    float dsum = 0.f;
#pragma unroll
    for (int k = 0; k < 4; k++){
      float4 va = *(const float4*)&wc2L[jg + sjq + 4*k];
      float sL0 = ra + va.x, sL1 = ra + va.y, sL2 = ra + va.z, sL3 = ra + va.w;
      float t20 = EXP2(sL0), t21 = EXP2(sL1), t22 = EXP2(sL2), t23 = EXP2(sL3);
      float w0 = sL0 > 0.f ? t20 : EXP2((t20 - 1.f)*L2E);
      float w1 = sL1 > 0.f ? t21 : EXP2((t21 - 1.f)*L2E);
      float w2 = sL2 > 0.f ? t22 : EXP2((t22 - 1.f)*L2E);
      float w3 = sL3 > 0.f ? t23 : EXP2((t23 - 1.f)*L2E);
      w0 = ((mb >> (4*k + 0)) & 1u) ? w0 : 0.f;
      w1 = ((mb >> (4*k + 1)) & 1u) ? w1 : 0.f;
      w2 = ((mb >> (4*k + 2)) & 1u) ? w2 : 0.f;
      w3 = ((mb >> (4*k + 3)) & 1u) ? w3 : 0.f;
      dsum += (w0 + w1) + (w2 + w3);
      if (k < 2){
        wlo[4*k]=(f16)w0; wlo[4*k+1]=(f16)w1; wlo[4*k+2]=(f16)w2; wlo[4*k+3]=(f16)w3;
      } else {
        whi[4*k-8]=(f16)w0; whi[4*k-7]=(f16)w1; whi[4*k-6]=(f16)w2; whi[4*k-5]=(f16)w3;
      }
    }
    *(f16x8*)&Ws[wsbase + ((wc0    ) ^ (si & 7))*8] = wlo;
    *(f16x8*)&Ws[wsbase + ((wc0 + 1) ^ (si & 7))*8] = whi;
    dsum += __shfl_xor(dsum, 1);
    dsum += __shfl_xor(dsum, 2);
    rden += dsum;
    __syncthreads();
    // wave w owns d-range w*32..w*32+31, all 64 i
#pragma unroll
    for (int ks = 0; ks < 2; ks++){
      int sc = (ks*4 + (qm >> 3)) ^ (rm & 7);
      f16x8 a[4], b[2];
#pragma unroll
      for (int mi = 0; mi < 4; mi++) a[mi] = *(const f16x8*)&Ws[(mi*16 + rm)*64 + sc*8];
#pragma unroll
      for (int fn = 0; fn < 2; fn++)
        b[fn] = *(const f16x8*)&Hs[(w*32 + fn*16 + rm)*64 + sc*8];
#pragma unroll
      for (int mi = 0; mi < 4; mi++)
#pragma unroll
        for (int fn = 0; fn < 2; fn++)
          acc[mi][fn] = __builtin_amdgcn_mfma_f32_16x16x32_f16(a[mi], b[fn], acc[mi][fn], 0, 0, 0);
    }
    __syncthreads();
  }
  if ((t & 3) == 0) atomicAdd(&den[i0 + si], rden);
  int quad = lane >> 4, cl = lane & 15;
#pragma unroll
  for (int mi = 0; mi < 4; mi++)
#pragma unroll
    for (int fn = 0; fn < 2; fn++){
      int rr = i0 + mi*16 + quad*4;
      int dc = w*32 + fn*16 + cl;
#pragma unroll
      for (int reg = 0; reg < 4; reg++)
        atomicAdd(&num[(size_t)(rr + reg)*D2 + dc], acc[mi][fn][reg]);
    }
}

// ---------------- E2: embed = l2norm(elu(num/den)) + conv_b ----------------
__global__ __launch_bounds__(256) void k_embed(
    const float* __restrict__ numc, const float* __restrict__ denc,
    const float* __restrict__ conv_b, float* __restrict__ embed){
  __shared__ float red[2][2];
  int t = threadIdx.x, g = t >> 7, c = t & 127;
  int r = blockIdx.x*2 + g;
  float e = eluf(numc[(size_t)r*D2 + c] / denc[r]);
  float ss = e*e;
#pragma unroll
  for (int o = 32; o > 0; o >>= 1) ss += __shfl_xor(ss, o);
  if ((t & 63) == 0) red[g][(t >> 6) & 1] = ss;
  __syncthreads();
  float invn = 1.f / fmaxf(sqrtf(red[g][0] + red[g][1]), 1e-12f);
  embed[(size_t)r*D2 + c] = e*invn + conv_b[c];
}

// ---------------- E3: two 128->128->64 elu MLPs, 32 rows/block, 4 rows/iter ----------------
__global__ __launch_bounds__(256) void k_mlp(
    const float* __restrict__ embed,
    const float* __restrict__ fw1, const float* __restrict__ fb1,
    const float* __restrict__ fw2, const float* __restrict__ fb2,
    const float* __restrict__ gw1, const float* __restrict__ gb1,
    const float* __restrict__ gw2, const float* __restrict__ gb2,
    float* __restrict__ tf, float* __restrict__ tg){
  const float* w1 = blockIdx.y ? gw1 : fw1;
  const float* b1 = blockIdx.y ? gb1 : fb1;
  const float* w2 = blockIdx.y ? gw2 : fw2;
  const float* b2 = blockIdx.y ? gb2 : fb2;
  float* out = blockIdx.y ? tg : tf;
  int t = threadIdx.x;
  int c = t & 127, kh = t >> 7;
  int o = t & 63, kh2 = t >> 6;
  float rw1[64];
#pragma unroll
  for (int i = 0; i < 64; i++) rw1[i] = w1[(kh*64 + i)*128 + c];
  float rw2[32];
#pragma unroll
  for (int i = 0; i < 32; i++) rw2[i] = w2[(kh2*32 + i)*64 + o];
  float bb1 = b1[c], bb2 = b2[o];
  __shared__ float erow[4][128];
  __shared__ float hidp[2][4][128];
  __shared__ float hid[4][128];
  __shared__ float outp[4][4][64];
  int r0 = blockIdx.x*32;
  for (int it = 0; it < 8; it++){
    int rbase = r0 + it*4;
    ((float2*)erow)[t] = ((const float2*)(embed + (size_t)rbase*128))[t];
    __syncthreads();
#pragma unroll
    for (int g = 0; g < 4; g++){
      float s = 0.f;
#pragma unroll
      for (int i = 0; i < 64; i++) s += erow[g][kh*64 + i]*rw1[i];
      hidp[kh][g][c] = s;
    }
    __syncthreads();
#pragma unroll
    for (int gg = 0; gg < 2; gg++){
      int g = kh + 2*gg;
      hid[g][c] = eluf(bb1 + hidp[0][g][c] + hidp[1][g][c]);
    }
    __syncthreads();
#pragma unroll
    for (int g = 0; g < 4; g++){
      float s = 0.f;
#pragma unroll
      for (int i = 0; i < 32; i++) s += hid[g][kh2*32 + i]*rw2[i];
      outp[kh2][g][o] = s;
    }
    __syncthreads();
    { int g = t >> 6;
      out[(size_t)(rbase + g)*64 + o] =
        eluf(bb2 + outp[0][g][o] + outp[1][g][o] + outp[2][g][o] + outp[3][g][o]); }
    __syncthreads();
  }
}

// ---------------- E4: pred = rowwise dot of gathered tf/tg (float4, 16 lanes/pair) ----------------
__global__ __launch_bounds__(256) void k_pred(
    const int* __restrict__ ts, const float4* __restrict__ tf4,
    const float4* __restrict__ tg4, float* __restrict__ out){
  int p = blockIdx.x*16 + (threadIdx.x >> 4);
  int l = threadIdx.x & 15;
  int i = ts[2*p], j = ts[2*p + 1];
  float4 a = tf4[(size_t)i*16 + l], b = tg4[(size_t)j*16 + l];
  float v = a.x*b.x + a.y*b.y + a.z*b.z + a.w*b.w;
  v += __shfl_xor(v, 1); v += __shfl_xor(v, 2);
  v += __shfl_xor(v, 4); v += __shfl_xor(v, 8);
  if (l == 0) out[p] = v;
}

// ---------------- workspace layout ----------------
#define OFF_MASK  ((size_t)0)
#define OFF_X16   ((size_t)8388608)
#define OFF_WT16  ((size_t)20971520)
#define OFF_HT16  ((size_t)21757952)
#define OFF_WH1   ((size_t)30146560)
#define OFF_WH2   ((size_t)30212096)
#define OFF_C1    ((size_t)30277632)
#define OFF_C2    ((size_t)30343168)
#define OFF_GMAX  ((size_t)30408704)
#define OFF_NUM1  ((size_t)30408960)
#define OFF_DEN1  ((size_t)47186176)
#define OFF_GT16  ((size_t)47251712)
#define OFF_WC1L  ((size_t)49348864)
#define OFF_WC2L  ((size_t)49381632)
#define OFF_NUMC  ((size_t)49414400)
#define OFF_DENC  ((size_t)53608704)
#define OFF_EMB   ((size_t)53641472)
#define OFF_TF    ((size_t)57835776)
#define OFF_TG    ((size_t)59932928)

extern "C" void kernel_launch(void* const* d_in, const int* in_sizes, int n_in,
                              void* d_out, int out_size, void* d_ws, size_t ws_size,
                              hipStream_t stream){
  const float* x      = (const float*)d_in[0];
  const int*   adj    = (const int*)d_in[1];
  const int*   ts     = (const int*)d_in[2];
  const float* head_W = (const float*)d_in[3];
  const float* head_a = (const float*)d_in[4];
  const float* head_b = (const float*)d_in[5];
  const float* conv_w = (const float*)d_in[6];
  const float* conv_cb= (const float*)d_in[7];
  const float* conv_a = (const float*)d_in[8];
  const float* conv_b = (const float*)d_in[9];
  const float* tf_w1  = (const float*)d_in[10];
  const float* tf_b1  = (const float*)d_in[11];
  const float* tf_w2  = (const float*)d_in[12];
  const float* tf_b2  = (const float*)d_in[13];
  const float* tg_w1  = (const float*)d_in[14];
  const float* tg_b1  = (const float*)d_in[15];
  const float* tg_w2  = (const float*)d_in[16];
  const float* tg_b2  = (const float*)d_in[17];
  float* outp = (float*)d_out;
  char* ws = (char*)d_ws;

  unsigned* maskw = (unsigned*)(ws + OFF_MASK);
  f16*   x16   = (f16*)(ws + OFF_X16);
  f16*   Wt16  = (f16*)(ws + OFF_WT16);
  f16*   hT16  = (f16*)(ws + OFF_HT16);
  float* wh1   = (float*)(ws + OFF_WH1);
  float* wh2   = (float*)(ws + OFF_WH2);
  float* c1    = (float*)(ws + OFF_C1);
  unsigned* gmax = (unsigned*)(ws + OFF_GMAX);
  float* num1  = (float*)(ws + OFF_NUM1);
  float* den1  = (float*)(ws + OFF_DEN1);
  f16*   gT16  = (f16*)(ws + OFF_GT16);
  float* wc1L  = (float*)(ws + OFF_WC1L);
  float* wc2L  = (float*)(ws + OFF_WC2L);
  float* numc  = (float*)(ws + OFF_NUMC);
  float* denc  = (float*)(ws + OFF_DENC);
  float* emb   = (float*)(ws + OFF_EMB);
  float* tf    = (float*)(ws + OFF_TF);
  float* tg    = (float*)(ws + OFF_TG);

  // zero atomic accumulators (ws is poisoned before every call)
  hipMemsetAsync(wh1, 0, 2*2*NN*sizeof(float), stream);            // wh1+wh2
  hipMemsetAsync(gmax, 0, 2*sizeof(unsigned), stream);
  hipMemsetAsync(num1, 0, (size_t)2*NN*D1*sizeof(float) + 2*NN*sizeof(float), stream); // num1+den1
  hipMemsetAsync(numc, 0, (size_t)NN*D2*sizeof(float) + NN*sizeof(float), stream);     // numc+denc

  k_prep     <<<DT + (NN*IND)/1024, 256, 0, stream>>>(x, x16, head_W, Wt16);
  k_gemm_pack<<<512 + NN*NN/1024, 256, 0, stream>>>(x16, Wt16, head_a, hT16, wh1, wh2,
                                                    (const int4*)adj, maskw);
  k_post     <<<(2*NN)/256, 256, 0, stream>>>(wh2, gmax, c1);
  k_agg_head <<<dim3(NN/64, JS1, 2), 256, 0, stream>>>(hT16, maskw, wh1, c1, gmax, num1, den1);
  k_merge_conv<<<NN/2, 256, 0, stream>>>(num1, den1, head_b, conv_w, conv_cb, conv_a, gT16, wc1L, wc2L);
  k_agg_conv <<<dim3(NN/64, 8), 256, 0, stream>>>(gT16, maskw, wc1L, wc2L, numc, denc);
  k_embed    <<<NN/2, 256, 0, stream>>>(numc, denc, conv_b, emb);
  k_mlp      <<<dim3(NN/32, 2), 256, 0, stream>>>(emb, tf_w1, tf_b1, tf_w2, tf_b2,
                                                  tg_w1, tg_b1, tg_w2, tg_b2, tf, tg);
  k_pred     <<<EPAIRS/16, 256, 0, stream>>>(ts, (const float4*)tf, (const float4*)tg, outp);
}

// Round 11
// 670.766 us; speedup vs baseline: 1.0316x; 1.0316x over previous
//
#include <hip/hip_runtime.h>

// GATCL: 2-head GAT (N=8192, D=256) + feature conv (K=129) + GAT(D=128) + 2 MLPs + pair dots.
// R13: revert to R9 (best measured, 672.9us) + keep only R12's harmless k_post fusion
// (gmax|colterms one wh2 pass). R12's gemm|pack fusion removed: pack's HBM stream under
// gemm extended gemm's critical path (-19us regression). All MFMA kernels = R9 verbatim.

typedef _Float16 f16;
typedef _Float16 f16x8 __attribute__((ext_vector_type(8)));
typedef float f32x4 __attribute__((ext_vector_type(4)));

#define DEV __device__ __forceinline__
#define L2E 1.4426950408889634f
#define NN 8192
#define IND 768
#define D1 256
#define DT 512
#define D2 128
#define KC 129
#define EPAIRS 100000
#define JS1 4

#if __has_builtin(__builtin_amdgcn_exp2f)
#define EXP2(x) __builtin_amdgcn_exp2f(x)
#else
#define EXP2(x) exp2f(x)
#endif

DEV float eluf(float x){ return x > 0.f ? x : EXP2(x*L2E) - 1.f; }

// async 16B global->LDS (LDS dest is wave-uniform base; lane writes base+lane*16)
DEV void gload_lds16(const void* g, void* l){
  __builtin_amdgcn_global_load_lds(
      (const __attribute__((address_space(1))) unsigned*)g,
      (__attribute__((address_space(3))) unsigned*)l, 16, 0, 0);
}

// ---------------- P0: pack adjacency (int32 0/1) into bit mask, int4 loads ----------------
__global__ __launch_bounds__(256) void k_pack(const int4* __restrict__ adj4, unsigned* __restrict__ maskw){
  int idx = blockIdx.x*256 + threadIdx.x;          // int4 index; j-flat = 4*idx
  int4 v = adj4[idx];
  unsigned n = (unsigned)(v.x > 0) | ((unsigned)(v.y > 0) << 1)
             | ((unsigned)(v.z > 0) << 2) | ((unsigned)(v.w > 0) << 3);
  n |= __shfl_xor(n, 1) << 4;    // lanes ≡0 mod 2 now hold a correct byte
  n |= __shfl_xor(n, 2) << 8;    // lanes ≡0 mod 4 hold correct 16 bits
  n |= __shfl_xor(n, 4) << 16;   // lanes ≡0 mod 8 hold correct 32 bits
  if ((threadIdx.x & 7) == 0) maskw[idx >> 3] = n;
}

// ---------------- P1: cast x to fp16 ----------------
__global__ __launch_bounds__(256) void k_cast_x(const float* __restrict__ x, f16* __restrict__ x16){
  int i = (blockIdx.x*256 + threadIdx.x)*4;
  float4 v = *(const float4*)(x + i);
  union { f16 h[4]; uint2 u; } p;
  p.h[0]=(f16)v.x; p.h[1]=(f16)v.y; p.h[2]=(f16)v.z; p.h[3]=(f16)v.w;
  *(uint2*)(x16 + i) = p.u;
}

// ---------------- P2: W' transpose+cast: Wt[n'=h*256+d][k] = head_W[h][k][d] ----------------
__global__ __launch_bounds__(256) void k_wt(const float* __restrict__ W, f16* __restrict__ Wt){
  int np = blockIdx.x; int h = np >> 8, d = np & 255;
  for (int k = threadIdx.x; k < IND; k += 256)
    Wt[(size_t)np*IND + k] = (f16)W[((size_t)h*IND + k)*D1 + d];
}

// ---------------- G1: h = x @ W' (8192x512), BK=64, write hT fp16 + wh1/wh2 atomics ----------------
// R9: staging via gload_lds16, As/Bs linear + chunk-XOR swizzle, (256,4).
__global__ __launch_bounds__(256, 4) void k_gemm_h(
    const f16* __restrict__ x16, const f16* __restrict__ Wt,
    const float* __restrict__ head_a,
    f16* __restrict__ hT, float* __restrict__ wh1, float* __restrict__ wh2){
  __shared__ f16 As[64*64];      // linear, 16B-chunk swizzled within each 128B row
  __shared__ f16 Bs[128*64];     // linear, 16B-chunk swizzled
  int m0 = blockIdx.x*64, n0 = blockIdx.y*128;
  int t = threadIdx.x, lane = t & 63, w = t >> 6;
  int wi = w >> 1, wd = w & 1;
  int rm = lane & 15, qm = (lane >> 4)*8;
  const int wb = t & ~63;        // wave-uniform staging base index
  f32x4 acc[2][4] = {};
  for (int k0 = 0; k0 < IND; k0 += 64){
#pragma unroll
    for (int p = 0; p < 2; p++){
      int idx = p*256 + t;
      int dr = idx >> 3, gch = (idx & 7) ^ (dr & 7);
      gload_lds16(&x16[(size_t)(m0 + dr)*IND + k0 + gch*8], &As[(p*256 + wb)*8]);
    }
#pragma unroll
    for (int p = 0; p < 4; p++){
      int idx = p*256 + t;
      int dr = idx >> 3, gch = (idx & 7) ^ (dr & 7);
      gload_lds16(&Wt[(size_t)(n0 + dr)*IND + k0 + gch*8], &Bs[(p*256 + wb)*8]);
    }
    __syncthreads();
#pragma unroll
    for (int ks = 0; ks < 2; ks++){
      int sc = (ks*4 + (qm >> 3)) ^ (rm & 7);  // swizzled 16B-chunk within row
      f16x8 a0 = *(const f16x8*)&As[(wi*32 + rm)*64 + sc*8];
      f16x8 a1 = *(const f16x8*)&As[(wi*32 + 16 + rm)*64 + sc*8];
#pragma unroll
      for (int fn = 0; fn < 4; fn++){
        f16x8 b = *(const f16x8*)&Bs[(wd*64 + fn*16 + rm)*64 + sc*8];
        acc[0][fn] = __builtin_amdgcn_mfma_f32_16x16x32_f16(a0, b, acc[0][fn], 0, 0, 0);
        acc[1][fn] = __builtin_amdgcn_mfma_f32_16x16x32_f16(a1, b, acc[1][fn], 0, 0, 0);
      }
    }
    __syncthreads();
  }
  int quad = lane >> 4, cl = lane & 15;
  int head = n0 >> 8;
  float a1v[4], a2v[4];
#pragma unroll
  for (int fn = 0; fn < 4; fn++){
    int d = (n0 & 255) + wd*64 + fn*16 + cl;
    a1v[fn] = head_a[head*DT + d];
    a2v[fn] = head_a[head*DT + D1 + d];
  }
  float p1[2][4], p2[2][4];
#pragma unroll
  for (int fi = 0; fi < 2; fi++){
#pragma unroll
    for (int fn = 0; fn < 4; fn++){
      int npg = n0 + wd*64 + fn*16 + cl;
      int mg = m0 + wi*32 + fi*16 + quad*4;
      union { f16 h[4]; uint2 u; } pk;
#pragma unroll
      for (int reg = 0; reg < 4; reg++) pk.h[reg] = (f16)acc[fi][fn][reg];
      *(uint2*)&hT[(size_t)npg*NN + mg] = pk.u;
    }
#pragma unroll
    for (int reg = 0; reg < 4; reg++){
      float s1 = 0.f, s2 = 0.f;
#pragma unroll
      for (int fn = 0; fn < 4; fn++){ s1 += acc[fi][fn][reg]*a1v[fn]; s2 += acc[fi][fn][reg]*a2v[fn]; }
      p1[fi][reg] = s1; p2[fi][reg] = s2;
    }
  }
#pragma unroll
  for (int o = 1; o < 16; o <<= 1){
#pragma unroll
    for (int fi = 0; fi < 2; fi++)
#pragma unroll
      for (int reg = 0; reg < 4; reg++){
        p1[fi][reg] += __shfl_xor(p1[fi][reg], o);
        p2[fi][reg] += __shfl_xor(p2[fi][reg], o);
      }
  }
  if (cl == 0){
#pragma unroll
    for (int fi = 0; fi < 2; fi++)
#pragma unroll
      for (int reg = 0; reg < 4; reg++){
        int mg = m0 + wi*32 + fi*16 + quad*4 + reg;
        atomicAdd(&wh1[head*NN + mg], p1[fi][reg]);
        atomicAdd(&wh2[head*NN + mg], p2[fi][reg]);
      }
  }
}

// ---------------- P4: gmax | colterms fused (one wh2 pass) ----------------
__global__ __launch_bounds__(256) void k_post(const float* __restrict__ wh2,
                                              unsigned* __restrict__ gmax,
                                              float* __restrict__ c1){
  int i = blockIdx.x*256 + threadIdx.x;    // over 2*NN; waves never straddle heads
  float v = wh2[i];
  c1[i] = v*L2E;
  int h = i >> 13;                          // i / NN
  float m = v;
#pragma unroll
  for (int o = 32; o > 0; o >>= 1) m = fmaxf(m, __shfl_xor(m, o));
  if ((threadIdx.x & 63) == 0){
    unsigned b = __float_as_uint(m);
    unsigned enc = (b & 0x80000000u) ? ~b : (b | 0x80000000u);
    atomicMax(gmax + h, enc);
  }
}

// ---------------- A1: head GAT aggregation. i-tile 64, full D=256, j-split 4 ----------------
// R8/R9 (best measured): LDS 40960 B, row terms in regs, c2 folded into FMA, 4 blocks/CU.
__global__ __launch_bounds__(256, 4) void k_agg_head(
    const f16* __restrict__ hT, const unsigned* __restrict__ maskw,
    const float* __restrict__ wh1, const float* __restrict__ c1,
    const unsigned* __restrict__ gmaxp,
    float* __restrict__ num, float* __restrict__ den){
  __shared__ f16 Hs[256*64];     // linear, 16B-chunk swizzled within each 128B row
  __shared__ f16 Ws[64*64];      // linear, 16B-chunk swizzled
  int head = blockIdx.z;
  int i0 = blockIdx.x*64;
  int jbase = blockIdx.y*(NN/JS1);
  const f16* hTh = hT + (size_t)head*D1*NN;
  int t = threadIdx.x, lane = t & 63, w = t >> 6;
  int rm = lane & 15, qm = (lane >> 4)*8;
  int si = t >> 2, sjq = (t & 3)*16;
  // per-row score terms (4 lanes per row; broadcast loads)
  unsigned e = gmaxp[head];
  float gmax = __uint_as_float((e & 0x80000000u) ? (e ^ 0x80000000u) : ~e);
  float u = wh1[head*NN + i0 + si];
  float sm = u + gmax;
  float M = (sm > 0.f ? sm : 0.2f*sm)*L2E;   // leaky(wh1+gmax) in log2 units
  float ra = u*L2E - M;                      // s1 = ra + c1[j]
  float rb = -0.8f*M;                        // s2 = 0.2*s1 + rb  (exact identity)
  const float* c1h = c1 + head*NN;
  const unsigned* mrowp = maskw + (size_t)(i0 + si)*(NN/32);
  float rden = 0.f;
  f32x4 acc[4][4] = {};
  const int wb = t & ~63;        // wave-uniform staging base index
  const int wsbase = si*64;
  const int wc0 = sjq >> 3;      // this thread's first 16B chunk in its Ws row
  for (int j0 = 0; j0 < NN/JS1; j0 += 64){
    int jg = jbase + j0;
    // stage Hs[d=256][j=64] via async DMA; per-lane global src picks chunk (c^(row&7))
#pragma unroll
    for (int p = 0; p < 8; p++){
      int idx = p*256 + t;
      int dr = idx >> 3, gch = (idx & 7) ^ (dr & 7);
      gload_lds16(hTh + (size_t)dr*NN + jg + gch*8, &Hs[(p*256 + wb)*8]);
    }
    // scores: streamed float4 reads (cache-resident), short live ranges
    unsigned mb = mrowp[(jg + sjq) >> 5] >> (sjq & 31);
    f16x8 wlo, whi;
    float dsum = 0.f;
#pragma unroll
    for (int k = 0; k < 4; k++){
      float4 va = *(const float4*)&c1h[jg + sjq + 4*k];
      float s0 = ra + va.x, s1 = ra + va.y, s2 = ra + va.z, s3 = ra + va.w;
      float w0 = EXP2(fmaxf(s0, fmaf(0.2f, s0, rb)));
      float w1 = EXP2(fmaxf(s1, fmaf(0.2f, s1, rb)));
      float w2 = EXP2(fmaxf(s2, fmaf(0.2f, s2, rb)));
      float w3 = EXP2(fmaxf(s3, fmaf(0.2f, s3, rb)));
      w0 = ((mb >> (4*k + 0)) & 1u) ? w0 : 0.f;
      w1 = ((mb >> (4*k + 1)) & 1u) ? w1 : 0.f;
      w2 = ((mb >> (4*k + 2)) & 1u) ? w2 : 0.f;
      w3 = ((mb >> (4*k + 3)) & 1u) ? w3 : 0.f;
      dsum += (w0 + w1) + (w2 + w3);
      if (k < 2){
        wlo[4*k]=(f16)w0; wlo[4*k+1]=(f16)w1; wlo[4*k+2]=(f16)w2; wlo[4*k+3]=(f16)w3;
      } else {
        whi[4*k-8]=(f16)w0; whi[4*k-7]=(f16)w1; whi[4*k-6]=(f16)w2; whi[4*k-5]=(f16)w3;
      }
    }
    *(f16x8*)&Ws[wsbase + ((wc0    ) ^ (si & 7))*8] = wlo;
    *(f16x8*)&Ws[wsbase + ((wc0 + 1) ^ (si & 7))*8] = whi;
    dsum += __shfl_xor(dsum, 1);
    dsum += __shfl_xor(dsum, 2);
    rden += dsum;
    __syncthreads();               // drains DMA (vmcnt) + Ws writes (lgkm)
    // MFMA: wave w owns d-range w*64..w*64+63, all 64 i
#pragma unroll
    for (int ks = 0; ks < 2; ks++){
      int sc = (ks*4 + (qm >> 3)) ^ (rm & 7);  // swizzled 16B-chunk within row
      f16x8 a[4], b[4];
#pragma unroll
      for (int mi = 0; mi < 4; mi++) a[mi] = *(const f16x8*)&Ws[(mi*16 + rm)*64 + sc*8];
#pragma unroll
      for (int fn = 0; fn < 4; fn++)
        b[fn] = *(const f16x8*)&Hs[(w*64 + fn*16 + rm)*64 + sc*8];
#pragma unroll
      for (int mi = 0; mi < 4; mi++)
#pragma unroll
        for (int fn = 0; fn < 4; fn++)
          acc[mi][fn] = __builtin_amdgcn_mfma_f32_16x16x32_f16(a[mi], b[fn], acc[mi][fn], 0, 0, 0);
    }
    __syncthreads();
  }
  if ((t & 3) == 0) atomicAdd(&den[head*NN + i0 + si], rden);
  int quad = lane >> 4, cl = lane & 15;
#pragma unroll
  for (int mi = 0; mi < 4; mi++)
#pragma unroll
    for (int fn = 0; fn < 4; fn++){
      int rr = i0 + mi*16 + quad*4;
      int dc = w*64 + fn*16 + cl;
#pragma unroll
      for (int reg = 0; reg < 4; reg++)
        atomicAdd(&num[((size_t)head*NN + rr + reg)*D1 + dc], acc[mi][fn][reg]);
    }
}

// ---------------- E1: merge heads -> z -> conv -> gT(fp16) + wc1L/wc2L ----------------
__global__ __launch_bounds__(256) void k_merge_conv(
    const float* __restrict__ num, const float* __restrict__ den,
    const float* __restrict__ head_b, const float* __restrict__ conv_w,
    const float* __restrict__ conv_cb, const float* __restrict__ conv_a,
    f16* __restrict__ gT, float* __restrict__ wc1L, float* __restrict__ wc2L){
  __shared__ float zrow[2][256];
  __shared__ float cw[KC];
  __shared__ float ca[256];
  __shared__ float red[2][2];
  __shared__ float red2[2][2][2];
  int t = threadIdx.x, g = t >> 7, c = t & 127;
  int r = blockIdx.x*2 + g;
  if (t < KC) cw[t] = conv_w[t];
  ca[t] = conv_a[t];
  float zv0 = 0.f, zv1 = 0.f;
#pragma unroll
  for (int h = 0; h < 2; h++){
    const float* nr = num + ((size_t)h*NN + r)*D1;
    float inv = 1.f / den[h*NN + r];
    float e0 = eluf(nr[c]*inv);
    float e1 = eluf(nr[c + 128]*inv);
    float ss = e0*e0 + e1*e1;
#pragma unroll
    for (int o = 32; o > 0; o >>= 1) ss += __shfl_xor(ss, o);
    if ((t & 63) == 0) red[g][(t >> 6) & 1] = ss;
    __syncthreads();
    float invn = 1.f / fmaxf(sqrtf(red[g][0] + red[g][1]), 1e-12f);
    zv0 += e0*invn + head_b[h*D1 + c];
    zv1 += e1*invn + head_b[h*D1 + 128 + c];
    __syncthreads();
  }
  zrow[g][c]       = eluf(0.5f*zv0);
  zrow[g][c + 128] = eluf(0.5f*zv1);
  __syncthreads();
  float s = conv_cb[0];
  for (int k = 0; k < KC; k++) s += zrow[g][c + k]*cw[k];
  gT[(size_t)c*NN + r] = (f16)s;
  float p1 = s*ca[c], p2 = s*ca[128 + c];
#pragma unroll
  for (int o = 32; o > 0; o >>= 1){ p1 += __shfl_xor(p1, o); p2 += __shfl_xor(p2, o); }
  if ((t & 63) == 0){ red2[g][(t >> 6) & 1][0] = p1; red2[g][(t >> 6) & 1][1] = p2; }
  __syncthreads();
  if ((t & 127) == 0){
    wc1L[r] = (red2[g][0][0] + red2[g][1][0])*L2E;
    wc2L[r] = (red2[g][0][1] + red2[g][1][1])*L2E;
  }
}

// ---------------- A2: conv GAT aggregation (elu scores, m=0). i-tile 64, D=128, j-split 8 ----------------
// R9: Ws linear-64 + chunk-XOR swizzle, rowc in regs, streamed scores. LDS 24576, (256,4).
__global__ __launch_bounds__(256, 4) void k_agg_conv(
    const f16* __restrict__ gT, const unsigned* __restrict__ maskw,
    const float* __restrict__ wc1L, const float* __restrict__ wc2L,
    float* __restrict__ num, float* __restrict__ den){
  __shared__ f16 Hs[128*64];     // linear, chunk-swizzled
  __shared__ f16 Ws[64*64];      // linear, chunk-swizzled
  int i0 = blockIdx.x*64;
  int jbase = blockIdx.y*1024;
  int t = threadIdx.x, lane = t & 63, w = t >> 6;
  int rm = lane & 15, qm = (lane >> 4)*8;
  int si = t >> 2, sjq = (t & 3)*16;
  float ra = wc1L[i0 + si];
  const unsigned* mrowp = maskw + (size_t)(i0 + si)*(NN/32);
  float rden = 0.f;
  f32x4 acc[4][2] = {};
  const int wb = t & ~63;
  const int wsbase = si*64;
  const int wc0 = sjq >> 3;
  for (int j0 = 0; j0 < 1024; j0 += 64){
    int jg = jbase + j0;
#pragma unroll
    for (int p = 0; p < 4; p++){
      int idx = p*256 + t;
      int dr = idx >> 3, gch = (idx & 7) ^ (dr & 7);
      gload_lds16(gT + (size_t)dr*NN + jg + gch*8, &Hs[(p*256 + wb)*8]);
    }
    unsigned mb = mrowp[(jg + sjq) >> 5] >> (sjq & 31);
    f16x8 wlo, whi;
    float dsum = 0.f;
#pragma unroll
    for (int k = 0; k < 4; k++){
      float4 va = *(const float4*)&wc2L[jg + sjq + 4*k];
      float sL0 = ra + va.x, sL1 = ra + va.y, sL2 = ra + va.z, sL3 = ra + va.w;
      float t20 = EXP2(sL0), t21 = EXP2(sL1), t22 = EXP2(sL2), t23 = EXP2(sL3);
      float w0 = sL0 > 0.f ? t20 : EXP2((t20 - 1.f)*L2E);
      float w1 = sL1 > 0.f ? t21 : EXP2((t21 - 1.f)*L2E);
      float w2 = sL2 > 0.f ? t22 : EXP2((t22 - 1.f)*L2E);
      float w3 = sL3 > 0.f ? t23 : EXP2((t23 - 1.f)*L2E);
      w0 = ((mb >> (4*k + 0)) & 1u) ? w0 : 0.f;
      w1 = ((mb >> (4*k + 1)) & 1u) ? w1 : 0.f;
      w2 = ((mb >> (4*k + 2)) & 1u) ? w2 : 0.f;
      w3 = ((mb >> (4*k + 3)) & 1u) ? w3 : 0.f;
      dsum += (w0 + w1) + (w2 + w3);
      if (k < 2){
        wlo[4*k]=(f16)w0; wlo[4*k+1]=(f16)w1; wlo[4*k+2]=(f16)w2; wlo[4*k+3]=(f16)w3;
      } else {
        whi[4*k-8]=(f16)w0; whi[4*k-7]=(f16)w1; whi[4*k-6]=(f16)w2; whi[4*k-5]=(f16)w3;
      }
    }
    *(f16x8*)&Ws[wsbase + ((wc0    ) ^ (si & 7))*8] = wlo;
    *(f16x8*)&Ws[wsbase + ((wc0 + 1) ^ (si & 7))*8] = whi;
    dsum += __shfl_xor(dsum, 1);
    dsum += __shfl_xor(dsum, 2);
    rden += dsum;
    __syncthreads();
    // wave w owns d-range w*32..w*32+31, all 64 i
#pragma unroll
    for (int ks = 0; ks < 2; ks++){
      int sc = (ks*4 + (qm >> 3)) ^ (rm & 7);
      f16x8 a[4], b[2];
#pragma unroll
      for (int mi = 0; mi < 4; mi++) a[mi] = *(const f16x8*)&Ws[(mi*16 + rm)*64 + sc*8];
#pragma unroll
      for (int fn = 0; fn < 2; fn++)
        b[fn] = *(const f16x8*)&Hs[(w*32 + fn*16 + rm)*64 + sc*8];
#pragma unroll
      for (int mi = 0; mi < 4; mi++)
#pragma unroll
        for (int fn = 0; fn < 2; fn++)
          acc[mi][fn] = __builtin_amdgcn_mfma_f32_16x16x32_f16(a[mi], b[fn], acc[mi][fn], 0, 0, 0);
    }
    __syncthreads();
  }
  if ((t & 3) == 0) atomicAdd(&den[i0 + si], rden);
  int quad = lane >> 4, cl = lane & 15;
#pragma unroll
  for (int mi = 0; mi < 4; mi++)
#pragma unroll
    for (int fn = 0; fn < 2; fn++){
      int rr = i0 + mi*16 + quad*4;
      int dc = w*32 + fn*16 + cl;
#pragma unroll
      for (int reg = 0; reg < 4; reg++)
        atomicAdd(&num[(size_t)(rr + reg)*D2 + dc], acc[mi][fn][reg]);
    }
}

// ---------------- E2: embed = l2norm(elu(num/den)) + conv_b ----------------
__global__ __launch_bounds__(256) void k_embed(
    const float* __restrict__ numc, const float* __restrict__ denc,
    const float* __restrict__ conv_b, float* __restrict__ embed){
  __shared__ float red[2][2];
  int t = threadIdx.x, g = t >> 7, c = t & 127;
  int r = blockIdx.x*2 + g;
  float e = eluf(numc[(size_t)r*D2 + c] / denc[r]);
  float ss = e*e;
#pragma unroll
  for (int o = 32; o > 0; o >>= 1) ss += __shfl_xor(ss, o);
  if ((t & 63) == 0) red[g][(t >> 6) & 1] = ss;
  __syncthreads();
  float invn = 1.f / fmaxf(sqrtf(red[g][0] + red[g][1]), 1e-12f);
  embed[(size_t)r*D2 + c] = e*invn + conv_b[c];
}

// ---------------- E3: two 128->128->64 elu MLPs, 32 rows/block, 4 rows/iter ----------------
__global__ __launch_bounds__(256) void k_mlp(
    const float* __restrict__ embed,
    const float* __restrict__ fw1, const float* __restrict__ fb1,
    const float* __restrict__ fw2, const float* __restrict__ fb2,
    const float* __restrict__ gw1, const float* __restrict__ gb1,
    const float* __restrict__ gw2, const float* __restrict__ gb2,
    float* __restrict__ tf, float* __restrict__ tg){
  const float* w1 = blockIdx.y ? gw1 : fw1;
  const float* b1 = blockIdx.y ? gb1 : fb1;
  const float* w2 = blockIdx.y ? gw2 : fw2;
  const float* b2 = blockIdx.y ? gb2 : fb2;
  float* out = blockIdx.y ? tg : tf;
  int t = threadIdx.x;
  int c = t & 127, kh = t >> 7;
  int o = t & 63, kh2 = t >> 6;
  float rw1[64];
#pragma unroll
  for (int i = 0; i < 64; i++) rw1[i] = w1[(kh*64 + i)*128 + c];
  float rw2[32];
#pragma unroll
  for (int i = 0; i < 32; i++) rw2[i] = w2[(kh2*32 + i)*64 + o];
  float bb1 = b1[c], bb2 = b2[o];
  __shared__ float erow[4][128];
  __shared__ float hidp[2][4][128];
  __shared__ float hid[4][128];
  __shared__ float outp[4][4][64];
  int r0 = blockIdx.x*32;
  for (int it = 0; it < 8; it++){
    int rbase = r0 + it*4;
    ((float2*)erow)[t] = ((const float2*)(embed + (size_t)rbase*128))[t];
    __syncthreads();
#pragma unroll
    for (int g = 0; g < 4; g++){
      float s = 0.f;
#pragma unroll
      for (int i = 0; i < 64; i++) s += erow[g][kh*64 + i]*rw1[i];
      hidp[kh][g][c] = s;
    }
    __syncthreads();
#pragma unroll
    for (int gg = 0; gg < 2; gg++){
      int g = kh + 2*gg;
      hid[g][c] = eluf(bb1 + hidp[0][g][c] + hidp[1][g][c]);
    }
    __syncthreads();
#pragma unroll
    for (int g = 0; g < 4; g++){
      float s = 0.f;
#pragma unroll
      for (int i = 0; i < 32; i++) s += hid[g][kh2*32 + i]*rw2[i];
      outp[kh2][g][o] = s;
    }
    __syncthreads();
    { int g = t >> 6;
      out[(size_t)(rbase + g)*64 + o] =
        eluf(bb2 + outp[0][g][o] + outp[1][g][o] + outp[2][g][o] + outp[3][g][o]); }
    __syncthreads();
  }
}

// ---------------- E4: pred = rowwise dot of gathered tf/tg (float4, 16 lanes/pair) ----------------
__global__ __launch_bounds__(256) void k_pred(
    const int* __restrict__ ts, const float4* __restrict__ tf4,
    const float4* __restrict__ tg4, float* __restrict__ out){
  int p = blockIdx.x*16 + (threadIdx.x >> 4);
  int l = threadIdx.x & 15;
  int i = ts[2*p], j = ts[2*p + 1];
  float4 a = tf4[(size_t)i*16 + l], b = tg4[(size_t)j*16 + l];
  float v = a.x*b.x + a.y*b.y + a.z*b.z + a.w*b.w;
  v += __shfl_xor(v, 1); v += __shfl_xor(v, 2);
  v += __shfl_xor(v, 4); v += __shfl_xor(v, 8);
  if (l == 0) out[p] = v;
}

// ---------------- workspace layout ----------------
#define OFF_MASK  ((size_t)0)
#define OFF_X16   ((size_t)8388608)
#define OFF_WT16  ((size_t)20971520)
#define OFF_HT16  ((size_t)21757952)
#define OFF_WH1   ((size_t)30146560)
#define OFF_WH2   ((size_t)30212096)
#define OFF_C1    ((size_t)30277632)
#define OFF_C2    ((size_t)30343168)
#define OFF_GMAX  ((size_t)30408704)
#define OFF_NUM1  ((size_t)30408960)
#define OFF_DEN1  ((size_t)47186176)
#define OFF_GT16  ((size_t)47251712)
#define OFF_WC1L  ((size_t)49348864)
#define OFF_WC2L  ((size_t)49381632)
#define OFF_NUMC  ((size_t)49414400)
#define OFF_DENC  ((size_t)53608704)
#define OFF_EMB   ((size_t)53641472)
#define OFF_TF    ((size_t)57835776)
#define OFF_TG    ((size_t)59932928)

extern "C" void kernel_launch(void* const* d_in, const int* in_sizes, int n_in,
                              void* d_out, int out_size, void* d_ws, size_t ws_size,
                              hipStream_t stream){
  const float* x      = (const float*)d_in[0];
  const int*   adj    = (const int*)d_in[1];
  const int*   ts     = (const int*)d_in[2];
  const float* head_W = (const float*)d_in[3];
  const float* head_a = (const float*)d_in[4];
  const float* head_b = (const float*)d_in[5];
  const float* conv_w = (const float*)d_in[6];
  const float* conv_cb= (const float*)d_in[7];
  const float* conv_a = (const float*)d_in[8];
  const float* conv_b = (const float*)d_in[9];
  const float* tf_w1  = (const float*)d_in[10];
  const float* tf_b1  = (const float*)d_in[11];
  const float* tf_w2  = (const float*)d_in[12];
  const float* tf_b2  = (const float*)d_in[13];
  const float* tg_w1  = (const float*)d_in[14];
  const float* tg_b1  = (const float*)d_in[15];
  const float* tg_w2  = (const float*)d_in[16];
  const float* tg_b2  = (const float*)d_in[17];
  float* outp = (float*)d_out;
  char* ws = (char*)d_ws;

  unsigned* maskw = (unsigned*)(ws + OFF_MASK);
  f16*   x16   = (f16*)(ws + OFF_X16);
  f16*   Wt16  = (f16*)(ws + OFF_WT16);
  f16*   hT16  = (f16*)(ws + OFF_HT16);
  float* wh1   = (float*)(ws + OFF_WH1);
  float* wh2   = (float*)(ws + OFF_WH2);
  float* c1    = (float*)(ws + OFF_C1);
  unsigned* gmax = (unsigned*)(ws + OFF_GMAX);
  float* num1  = (float*)(ws + OFF_NUM1);
  float* den1  = (float*)(ws + OFF_DEN1);
  f16*   gT16  = (f16*)(ws + OFF_GT16);
  float* wc1L  = (float*)(ws + OFF_WC1L);
  float* wc2L  = (float*)(ws + OFF_WC2L);
  float* numc  = (float*)(ws + OFF_NUMC);
  float* denc  = (float*)(ws + OFF_DENC);
  float* emb   = (float*)(ws + OFF_EMB);
  float* tf    = (float*)(ws + OFF_TF);
  float* tg    = (float*)(ws + OFF_TG);

  // zero atomic accumulators (ws is poisoned before every call)
  hipMemsetAsync(wh1, 0, 2*2*NN*sizeof(float), stream);            // wh1+wh2
  hipMemsetAsync(gmax, 0, 2*sizeof(unsigned), stream);
  hipMemsetAsync(num1, 0, (size_t)2*NN*D1*sizeof(float) + 2*NN*sizeof(float), stream); // num1+den1
  hipMemsetAsync(numc, 0, (size_t)NN*D2*sizeof(float) + NN*sizeof(float), stream);     // numc+denc

  k_pack    <<<NN*NN/1024, 256, 0, stream>>>((const int4*)adj, maskw);
  k_cast_x  <<<(NN*IND)/(256*4), 256, 0, stream>>>(x, x16);
  k_wt      <<<DT, 256, 0, stream>>>(head_W, Wt16);
  k_gemm_h  <<<dim3(NN/64, DT/128), 256, 0, stream>>>(x16, Wt16, head_a, hT16, wh1, wh2);
  k_post    <<<(2*NN)/256, 256, 0, stream>>>(wh2, gmax, c1);
  k_agg_head<<<dim3(NN/64, JS1, 2), 256, 0, stream>>>(hT16, maskw, wh1, c1, gmax, num1, den1);
  k_merge_conv<<<NN/2, 256, 0, stream>>>(num1, den1, head_b, conv_w, conv_cb, conv_a, gT16, wc1L, wc2L);
  k_agg_conv<<<dim3(NN/64, 8), 256, 0, stream>>>(gT16, maskw, wc1L, wc2L, numc, denc);
  k_embed   <<<NN/2, 256, 0, stream>>>(numc, denc, conv_b, emb);
  k_mlp     <<<dim3(NN/32, 2), 256, 0, stream>>>(emb, tf_w1, tf_b1, tf_w2, tf_b2,
                                                 tg_w1, tg_b1, tg_w2, tg_b2, tf, tg);
  k_pred    <<<EPAIRS/16, 256, 0, stream>>>(ts, (const float4*)tf, (const float4*)tg, outp);
}

// Round 12
// 655.377 us; speedup vs baseline: 1.0558x; 1.0235x over previous
//
#include <hip/hip_runtime.h>

// GATCL: 2-head GAT (N=8192, D=256) + feature conv (K=129) + GAT(D=128) + 2 MLPs + pair dots.
// R14: R13 compute kernels verbatim (confirmed plateau). Dispatch-count reduction:
// k_init = pack | cast_x | wt | zero(wh1,wh2,gmax,num1,den1,numc,denc) in ONE launch
// (all bandwidth-bound, all pre-gemm — no MFMA co-residency, unlike R12's failed fusion).
// 15 dispatches -> 9.

typedef _Float16 f16;
typedef _Float16 f16x8 __attribute__((ext_vector_type(8)));
typedef float f32x4 __attribute__((ext_vector_type(4)));

#define DEV __device__ __forceinline__
#define L2E 1.4426950408889634f
#define NN 8192
#define IND 768
#define D1 256
#define DT 512
#define D2 128
#define KC 129
#define EPAIRS 100000
#define JS1 4

#if __has_builtin(__builtin_amdgcn_exp2f)
#define EXP2(x) __builtin_amdgcn_exp2f(x)
#else
#define EXP2(x) exp2f(x)
#endif

DEV float eluf(float x){ return x > 0.f ? x : EXP2(x*L2E) - 1.f; }

// async 16B global->LDS (LDS dest is wave-uniform base; lane writes base+lane*16)
DEV void gload_lds16(const void* g, void* l){
  __builtin_amdgcn_global_load_lds(
      (const __attribute__((address_space(1))) unsigned*)g,
      (__attribute__((address_space(3))) unsigned*)l, 16, 0, 0);
}

// ---------------- INIT: pack | cast_x | wt | zero accumulators — one launch ----------------
// Block partition: [0,65536) pack; [65536,71680) cast; [71680,72192) wt;
// [72192,73220) zero num1+den1 (16,842,752 B); [73220,73478) zero numc+denc (4,227,072 B);
// [73478,73486) zero wh1+wh2 (131,072 B; block 73478/t0 also zeros gmax).
#define IB_PACK  65536
#define IB_CAST  (IB_PACK + 6144)
#define IB_WT    (IB_CAST + 512)
#define IB_Z1    (IB_WT + 1028)
#define IB_Z2    (IB_Z1 + 258)
#define IB_TOT   (IB_Z2 + 8)
__global__ __launch_bounds__(256) void k_init(
    const int4* __restrict__ adj4, unsigned* __restrict__ maskw,
    const float* __restrict__ x, f16* __restrict__ x16,
    const float* __restrict__ W, f16* __restrict__ Wt,
    float* __restrict__ wh1, unsigned* __restrict__ gmax,
    float* __restrict__ num1, float* __restrict__ numc){
  int b = blockIdx.x, t = threadIdx.x;
  if (b < IB_PACK){                      // pack adjacency into bit mask
    int idx = b*256 + t;                 // int4 index; j-flat = 4*idx
    int4 v = adj4[idx];
    unsigned n = (unsigned)(v.x > 0) | ((unsigned)(v.y > 0) << 1)
               | ((unsigned)(v.z > 0) << 2) | ((unsigned)(v.w > 0) << 3);
    n |= __shfl_xor(n, 1) << 4;
    n |= __shfl_xor(n, 2) << 8;
    n |= __shfl_xor(n, 4) << 16;
    if ((t & 7) == 0) maskw[idx >> 3] = n;
  } else if (b < IB_CAST){               // cast x to fp16
    int i = ((b - IB_PACK)*256 + t)*4;
    float4 v = *(const float4*)(x + i);
    union { f16 h[4]; uint2 u; } p;
    p.h[0]=(f16)v.x; p.h[1]=(f16)v.y; p.h[2]=(f16)v.z; p.h[3]=(f16)v.w;
    *(uint2*)(x16 + i) = p.u;
  } else if (b < IB_WT){                 // Wt[n'=h*256+d][k] = W[h][k][d]
    int np = b - IB_CAST; int h = np >> 8, d = np & 255;
    for (int k = t; k < IND; k += 256)
      Wt[(size_t)np*IND + k] = (f16)W[((size_t)h*IND + k)*D1 + d];
  } else {                               // zero accumulators, 16 KB/block float4 stores
    char* p; int rb;
    if (b < IB_Z1){ p = (char*)num1; rb = b - IB_WT; }
    else if (b < IB_Z2){ p = (char*)numc; rb = b - IB_Z1; }
    else { p = (char*)wh1; rb = b - IB_Z2;
           if (rb == 0 && t == 0){ gmax[0] = 0u; gmax[1] = 0u; } }
    float4 z = {0.f, 0.f, 0.f, 0.f};
    float4* q = (float4*)(p + (size_t)rb*16384);
#pragma unroll
    for (int k2 = 0; k2 < 4; k2++) q[k2*256 + t] = z;
  }
}

// ---------------- G1: h = x @ W' (8192x512), BK=64, write hT fp16 + wh1/wh2 atomics ----------------
// R9: staging via gload_lds16, As/Bs linear + chunk-XOR swizzle, (256,4).
__global__ __launch_bounds__(256, 4) void k_gemm_h(
    const f16* __restrict__ x16, const f16* __restrict__ Wt,
    const float* __restrict__ head_a,
    f16* __restrict__ hT, float* __restrict__ wh1, float* __restrict__ wh2){
  __shared__ f16 As[64*64];      // linear, 16B-chunk swizzled within each 128B row
  __shared__ f16 Bs[128*64];     // linear, 16B-chunk swizzled
  int m0 = blockIdx.x*64, n0 = blockIdx.y*128;
  int t = threadIdx.x, lane = t & 63, w = t >> 6;
  int wi = w >> 1, wd = w & 1;
  int rm = lane & 15, qm = (lane >> 4)*8;
  const int wb = t & ~63;        // wave-uniform staging base index
  f32x4 acc[2][4] = {};
  for (int k0 = 0; k0 < IND; k0 += 64){
#pragma unroll
    for (int p = 0; p < 2; p++){
      int idx = p*256 + t;
      int dr = idx >> 3, gch = (idx & 7) ^ (dr & 7);
      gload_lds16(&x16[(size_t)(m0 + dr)*IND + k0 + gch*8], &As[(p*256 + wb)*8]);
    }
#pragma unroll
    for (int p = 0; p < 4; p++){
      int idx = p*256 + t;
      int dr = idx >> 3, gch = (idx & 7) ^ (dr & 7);
      gload_lds16(&Wt[(size_t)(n0 + dr)*IND + k0 + gch*8], &Bs[(p*256 + wb)*8]);
    }
    __syncthreads();
#pragma unroll
    for (int ks = 0; ks < 2; ks++){
      int sc = (ks*4 + (qm >> 3)) ^ (rm & 7);  // swizzled 16B-chunk within row
      f16x8 a0 = *(const f16x8*)&As[(wi*32 + rm)*64 + sc*8];
      f16x8 a1 = *(const f16x8*)&As[(wi*32 + 16 + rm)*64 + sc*8];
#pragma unroll
      for (int fn = 0; fn < 4; fn++){
        f16x8 b = *(const f16x8*)&Bs[(wd*64 + fn*16 + rm)*64 + sc*8];
        acc[0][fn] = __builtin_amdgcn_mfma_f32_16x16x32_f16(a0, b, acc[0][fn], 0, 0, 0);
        acc[1][fn] = __builtin_amdgcn_mfma_f32_16x16x32_f16(a1, b, acc[1][fn], 0, 0, 0);
      }
    }
    __syncthreads();
  }
  int quad = lane >> 4, cl = lane & 15;
  int head = n0 >> 8;
  float a1v[4], a2v[4];
#pragma unroll
  for (int fn = 0; fn < 4; fn++){
    int d = (n0 & 255) + wd*64 + fn*16 + cl;
    a1v[fn] = head_a[head*DT + d];
    a2v[fn] = head_a[head*DT + D1 + d];
  }
  float p1[2][4], p2[2][4];
#pragma unroll
  for (int fi = 0; fi < 2; fi++){
#pragma unroll
    for (int fn = 0; fn < 4; fn++){
      int npg = n0 + wd*64 + fn*16 + cl;
      int mg = m0 + wi*32 + fi*16 + quad*4;
      union { f16 h[4]; uint2 u; } pk;
#pragma unroll
      for (int reg = 0; reg < 4; reg++) pk.h[reg] = (f16)acc[fi][fn][reg];
      *(uint2*)&hT[(size_t)npg*NN + mg] = pk.u;
    }
#pragma unroll
    for (int reg = 0; reg < 4; reg++){
      float s1 = 0.f, s2 = 0.f;
#pragma unroll
      for (int fn = 0; fn < 4; fn++){ s1 += acc[fi][fn][reg]*a1v[fn]; s2 += acc[fi][fn][reg]*a2v[fn]; }
      p1[fi][reg] = s1; p2[fi][reg] = s2;
    }
  }
#pragma unroll
  for (int o = 1; o < 16; o <<= 1){
#pragma unroll
    for (int fi = 0; fi < 2; fi++)
#pragma unroll
      for (int reg = 0; reg < 4; reg++){
        p1[fi][reg] += __shfl_xor(p1[fi][reg], o);
        p2[fi][reg] += __shfl_xor(p2[fi][reg], o);
      }
  }
  if (cl == 0){
#pragma unroll
    for (int fi = 0; fi < 2; fi++)
#pragma unroll
      for (int reg = 0; reg < 4; reg++){
        int mg = m0 + wi*32 + fi*16 + quad*4 + reg;
        atomicAdd(&wh1[head*NN + mg], p1[fi][reg]);
        atomicAdd(&wh2[head*NN + mg], p2[fi][reg]);
      }
  }
}

// ---------------- P4: gmax | colterms fused (one wh2 pass) ----------------
__global__ __launch_bounds__(256) void k_post(const float* __restrict__ wh2,
                                              unsigned* __restrict__ gmax,
                                              float* __restrict__ c1){
  int i = blockIdx.x*256 + threadIdx.x;    // over 2*NN; waves never straddle heads
  float v = wh2[i];
  c1[i] = v*L2E;
  int h = i >> 13;                          // i / NN
  float m = v;
#pragma unroll
  for (int o = 32; o > 0; o >>= 1) m = fmaxf(m, __shfl_xor(m, o));
  if ((threadIdx.x & 63) == 0){
    unsigned b = __float_as_uint(m);
    unsigned enc = (b & 0x80000000u) ? ~b : (b | 0x80000000u);
    atomicMax(gmax + h, enc);
  }
}

// ---------------- A1: head GAT aggregation. i-tile 64, full D=256, j-split 4 ----------------
// R8/R9 (best measured): LDS 40960 B, row terms in regs, c2 folded into FMA, 4 blocks/CU.
__global__ __launch_bounds__(256, 4) void k_agg_head(
    const f16* __restrict__ hT, const unsigned* __restrict__ maskw,
    const float* __restrict__ wh1, const float* __restrict__ c1,
    const unsigned* __restrict__ gmaxp,
    float* __restrict__ num, float* __restrict__ den){
  __shared__ f16 Hs[256*64];     // linear, 16B-chunk swizzled within each 128B row
  __shared__ f16 Ws[64*64];      // linear, 16B-chunk swizzled
  int head = blockIdx.z;
  int i0 = blockIdx.x*64;
  int jbase = blockIdx.y*(NN/JS1);
  const f16* hTh = hT + (size_t)head*D1*NN;
  int t = threadIdx.x, lane = t & 63, w = t >> 6;
  int rm = lane & 15, qm = (lane >> 4)*8;
  int si = t >> 2, sjq = (t & 3)*16;
  // per-row score terms (4 lanes per row; broadcast loads)
  unsigned e = gmaxp[head];
  float gmax = __uint_as_float((e & 0x80000000u) ? (e ^ 0x80000000u) : ~e);
  float u = wh1[head*NN + i0 + si];
  float sm = u + gmax;
  float M = (sm > 0.f ? sm : 0.2f*sm)*L2E;   // leaky(wh1+gmax) in log2 units
  float ra = u*L2E - M;                      // s1 = ra + c1[j]
  float rb = -0.8f*M;                        // s2 = 0.2*s1 + rb  (exact identity)
  const float* c1h = c1 + head*NN;
  const unsigned* mrowp = maskw + (size_t)(i0 + si)*(NN/32);
  float rden = 0.f;
  f32x4 acc[4][4] = {};
  const int wb = t & ~63;        // wave-uniform staging base index
  const int wsbase = si*64;
  const int wc0 = sjq >> 3;      // this thread's first 16B chunk in its Ws row
  for (int j0 = 0; j0 < NN/JS1; j0 += 64){
    int jg = jbase + j0;
    // stage Hs[d=256][j=64] via async DMA; per-lane global src picks chunk (c^(row&7))
#pragma unroll
    for (int p = 0; p < 8; p++){
      int idx = p*256 + t;
      int dr = idx >> 3, gch = (idx & 7) ^ (dr & 7);
      gload_lds16(hTh + (size_t)dr*NN + jg + gch*8, &Hs[(p*256 + wb)*8]);
    }
    // scores: streamed float4 reads (cache-resident), short live ranges
    unsigned mb = mrowp[(jg + sjq) >> 5] >> (sjq & 31);
    f16x8 wlo, whi;
    float dsum = 0.f;
#pragma unroll
    for (int k = 0; k < 4; k++){
      float4 va = *(const float4*)&c1h[jg + sjq + 4*k];
      float s0 = ra + va.x, s1 = ra + va.y, s2 = ra + va.z, s3 = ra + va.w;
      float w0 = EXP2(fmaxf(s0, fmaf(0.2f, s0, rb)));
      float w1 = EXP2(fmaxf(s1, fmaf(0.2f, s1, rb)));
      float w2 = EXP2(fmaxf(s2, fmaf(0.2f, s2, rb)));
      float w3 = EXP2(fmaxf(s3, fmaf(0.2f, s3, rb)));
      w0 = ((mb >> (4*k + 0)) & 1u) ? w0 : 0.f;
      w1 = ((mb >> (4*k + 1)) & 1u) ? w1 : 0.f;
      w2 = ((mb >> (4*k + 2)) & 1u) ? w2 : 0.f;
      w3 = ((mb >> (4*k + 3)) & 1u) ? w3 : 0.f;
      dsum += (w0 + w1) + (w2 + w3);
      if (k < 2){
        wlo[4*k]=(f16)w0; wlo[4*k+1]=(f16)w1; wlo[4*k+2]=(f16)w2; wlo[4*k+3]=(f16)w3;
      } else {
        whi[4*k-8]=(f16)w0; whi[4*k-7]=(f16)w1; whi[4*k-6]=(f16)w2; whi[4*k-5]=(f16)w3;
      }
    }
    *(f16x8*)&Ws[wsbase + ((wc0    ) ^ (si & 7))*8] = wlo;
    *(f16x8*)&Ws[wsbase + ((wc0 + 1) ^ (si & 7))*8] = whi;
    dsum += __shfl_xor(dsum, 1);
    dsum += __shfl_xor(dsum, 2);
    rden += dsum;
    __syncthreads();               // drains DMA (vmcnt) + Ws writes (lgkm)
    // MFMA: wave w owns d-range w*64..w*64+63, all 64 i
#pragma unroll
    for (int ks = 0; ks < 2; ks++){
      int sc = (ks*4 + (qm >> 3)) ^ (rm & 7);  // swizzled 16B-chunk within row
      f16x8 a[4], b[4];
#pragma unroll
      for (int mi = 0; mi < 4; mi++) a[mi] = *(const f16x8*)&Ws[(mi*16 + rm)*64 + sc*8];
#pragma unroll
      for (int fn = 0; fn < 4; fn++)
        b[fn] = *(const f16x8*)&Hs[(w*64 + fn*16 + rm)*64 + sc*8];
#pragma unroll
      for (int mi = 0; mi < 4; mi++)
#pragma unroll
        for (int fn = 0; fn < 4; fn++)
          acc[mi][fn] = __builtin_amdgcn_mfma_f32_16x16x32_f16(a[mi], b[fn], acc[mi][fn], 0, 0, 0);
    }
    __syncthreads();
  }
  if ((t & 3) == 0) atomicAdd(&den[head*NN + i0 + si], rden);
  int quad = lane >> 4, cl = lane & 15;
#pragma unroll
  for (int mi = 0; mi < 4; mi++)
#pragma unroll
    for (int fn = 0; fn < 4; fn++){
      int rr = i0 + mi*16 + quad*4;
      int dc = w*64 + fn*16 + cl;
#pragma unroll
      for (int reg = 0; reg < 4; reg++)
        atomicAdd(&num[((size_t)head*NN + rr + reg)*D1 + dc], acc[mi][fn][reg]);
    }
}

// ---------------- E1: merge heads -> z -> conv -> gT(fp16) + wc1L/wc2L ----------------
__global__ __launch_bounds__(256) void k_merge_conv(
    const float* __restrict__ num, const float* __restrict__ den,
    const float* __restrict__ head_b, const float* __restrict__ conv_w,
    const float* __restrict__ conv_cb, const float* __restrict__ conv_a,
    f16* __restrict__ gT, float* __restrict__ wc1L, float* __restrict__ wc2L){
  __shared__ float zrow[2][256];
  __shared__ float cw[KC];
  __shared__ float ca[256];
  __shared__ float red[2][2];
  __shared__ float red2[2][2][2];
  int t = threadIdx.x, g = t >> 7, c = t & 127;
  int r = blockIdx.x*2 + g;
  if (t < KC) cw[t] = conv_w[t];
  ca[t] = conv_a[t];
  float zv0 = 0.f, zv1 = 0.f;
#pragma unroll
  for (int h = 0; h < 2; h++){
    const float* nr = num + ((size_t)h*NN + r)*D1;
    float inv = 1.f / den[h*NN + r];
    float e0 = eluf(nr[c]*inv);
    float e1 = eluf(nr[c + 128]*inv);
    float ss = e0*e0 + e1*e1;
#pragma unroll
    for (int o = 32; o > 0; o >>= 1) ss += __shfl_xor(ss, o);
    if ((t & 63) == 0) red[g][(t >> 6) & 1] = ss;
    __syncthreads();
    float invn = 1.f / fmaxf(sqrtf(red[g][0] + red[g][1]), 1e-12f);
    zv0 += e0*invn + head_b[h*D1 + c];
    zv1 += e1*invn + head_b[h*D1 + 128 + c];
    __syncthreads();
  }
  zrow[g][c]       = eluf(0.5f*zv0);
  zrow[g][c + 128] = eluf(0.5f*zv1);
  __syncthreads();
  float s = conv_cb[0];
  for (int k = 0; k < KC; k++) s += zrow[g][c + k]*cw[k];
  gT[(size_t)c*NN + r] = (f16)s;
  float p1 = s*ca[c], p2 = s*ca[128 + c];
#pragma unroll
  for (int o = 32; o > 0; o >>= 1){ p1 += __shfl_xor(p1, o); p2 += __shfl_xor(p2, o); }
  if ((t & 63) == 0){ red2[g][(t >> 6) & 1][0] = p1; red2[g][(t >> 6) & 1][1] = p2; }
  __syncthreads();
  if ((t & 127) == 0){
    wc1L[r] = (red2[g][0][0] + red2[g][1][0])*L2E;
    wc2L[r] = (red2[g][0][1] + red2[g][1][1])*L2E;
  }
}

// ---------------- A2: conv GAT aggregation (elu scores, m=0). i-tile 64, D=128, j-split 8 ----------------
// R9: Ws linear-64 + chunk-XOR swizzle, rowc in regs, streamed scores. LDS 24576, (256,4).
__global__ __launch_bounds__(256, 4) void k_agg_conv(
    const f16* __restrict__ gT, const unsigned* __restrict__ maskw,
    const float* __restrict__ wc1L, const float* __restrict__ wc2L,
    float* __restrict__ num, float* __restrict__ den){
  __shared__ f16 Hs[128*64];     // linear, chunk-swizzled
  __shared__ f16 Ws[64*64];      // linear, chunk-swizzled
  int i0 = blockIdx.x*64;
  int jbase = blockIdx.y*1024;
  int t = threadIdx.x, lane = t & 63, w = t >> 6;
  int rm = lane & 15, qm = (lane >> 4)*8;
  int si = t >> 2, sjq = (t & 3)*16;
  float ra = wc1L[i0 + si];
  const unsigned* mrowp = maskw + (size_t)(i0 + si)*(NN/32);
  float rden = 0.f;
  f32x4 acc[4][2] = {};
  const int wb = t & ~63;
  const int wsbase = si*64;
  const int wc0 = sjq >> 3;
  for (int j0 = 0; j0 < 1024; j0 += 64){
    int jg = jbase + j0;
#pragma unroll
    for (int p = 0; p < 4; p++){
      int idx = p*256 + t;
      int dr = idx >> 3, gch = (idx & 7) ^ (dr & 7);
      gload_lds16(gT + (size_t)dr*NN + jg + gch*8, &Hs[(p*256 + wb)*8]);
    }
    unsigned mb = mrowp[(jg + sjq) >> 5] >> (sjq & 31);
    f16x8 wlo, whi;
    float dsum = 0.f;
#pragma unroll
    for (int k = 0; k < 4; k++){
      float4 va = *(const float4*)&wc2L[jg + sjq + 4*k];
      float sL0 = ra + va.x, sL1 = ra + va.y, sL2 = ra + va.z, sL3 = ra + va.w;
      float t20 = EXP2(sL0), t21 = EXP2(sL1), t22 = EXP2(sL2), t23 = EXP2(sL3);
      float w0 = sL0 > 0.f ? t20 : EXP2((t20 - 1.f)*L2E);
      float w1 = sL1 > 0.f ? t21 : EXP2((t21 - 1.f)*L2E);
      float w2 = sL2 > 0.f ? t22 : EXP2((t22 - 1.f)*L2E);
      float w3 = sL3 > 0.f ? t23 : EXP2((t23 - 1.f)*L2E);
      w0 = ((mb >> (4*k + 0)) & 1u) ? w0 : 0.f;
      w1 = ((mb >> (4*k + 1)) & 1u) ? w1 : 0.f;
      w2 = ((mb >> (4*k + 2)) & 1u) ? w2 : 0.f;
      w3 = ((mb >> (4*k + 3)) & 1u) ? w3 : 0.f;
      dsum += (w0 + w1) + (w2 + w3);
      if (k < 2){
        wlo[4*k]=(f16)w0; wlo[4*k+1]=(f16)w1; wlo[4*k+2]=(f16)w2; wlo[4*k+3]=(f16)w3;
      } else {
        whi[4*k-8]=(f16)w0; whi[4*k-7]=(f16)w1; whi[4*k-6]=(f16)w2; whi[4*k-5]=(f16)w3;
      }
    }
    *(f16x8*)&Ws[wsbase + ((wc0    ) ^ (si & 7))*8] = wlo;
    *(f16x8*)&Ws[wsbase + ((wc0 + 1) ^ (si & 7))*8] = whi;
    dsum += __shfl_xor(dsum, 1);
    dsum += __shfl_xor(dsum, 2);
    rden += dsum;
    __syncthreads();
    // wave w owns d-range w*32..w*32+31, all 64 i
#pragma unroll
    for (int ks = 0; ks < 2; ks++){
      int sc = (ks*4 + (qm >> 3)) ^ (rm & 7);
      f16x8 a[4], b[2];
#pragma unroll
      for (int mi = 0; mi < 4; mi++) a[mi] = *(const f16x8*)&Ws[(mi*16 + rm)*64 + sc*8];
#pragma unroll
      for (int fn = 0; fn < 2; fn++)
        b[fn] = *(const f16x8*)&Hs[(w*32 + fn*16 + rm)*64 + sc*8];
#pragma unroll
      for (int mi = 0; mi < 4; mi++)
#pragma unroll
        for (int fn = 0; fn < 2; fn++)
          acc[mi][fn] = __builtin_amdgcn_mfma_f32_16x16x32_f16(a[mi], b[fn], acc[mi][fn], 0, 0, 0);
    }
    __syncthreads();
  }
  if ((t & 3) == 0) atomicAdd(&den[i0 + si], rden);
  int quad = lane >> 4, cl = lane & 15;
#pragma unroll
  for (int mi = 0; mi < 4; mi++)
#pragma unroll
    for (int fn = 0; fn < 2; fn++){
      int rr = i0 + mi*16 + quad*4;
      int dc = w*32 + fn*16 + cl;
#pragma unroll
      for (int reg = 0; reg < 4; reg++)
        atomicAdd(&num[(size_t)(rr + reg)*D2 + dc], acc[mi][fn][reg]);
    }
}

// ---------------- E2: embed = l2norm(elu(num/den)) + conv_b ----------------
__global__ __launch_bounds__(256) void k_embed(
    const float* __restrict__ numc, const float* __restrict__ denc,
    const float* __restrict__ conv_b, float* __restrict__ embed){
  __shared__ float red[2][2];
  int t = threadIdx.x, g = t >> 7, c = t & 127;
  int r = blockIdx.x*2 + g;
  float e = eluf(numc[(size_t)r*D2 + c] / denc[r]);
  float ss = e*e;
#pragma unroll
  for (int o = 32; o > 0; o >>= 1) ss += __shfl_xor(ss, o);
  if ((t & 63) == 0) red[g][(t >> 6) & 1] = ss;
  __syncthreads();
  float invn = 1.f / fmaxf(sqrtf(red[g][0] + red[g][1]), 1e-12f);
  embed[(size_t)r*D2 + c] = e*invn + conv_b[c];
}

// ---------------- E3: two 128->128->64 elu MLPs, 32 rows/block, 4 rows/iter ----------------
__global__ __launch_bounds__(256) void k_mlp(
    const float* __restrict__ embed,
    const float* __restrict__ fw1, const float* __restrict__ fb1,
    const float* __restrict__ fw2, const float* __restrict__ fb2,
    const float* __restrict__ gw1, const float* __restrict__ gb1,
    const float* __restrict__ gw2, const float* __restrict__ gb2,
    float* __restrict__ tf, float* __restrict__ tg){
  const float* w1 = blockIdx.y ? gw1 : fw1;
  const float* b1 = blockIdx.y ? gb1 : fb1;
  const float* w2 = blockIdx.y ? gw2 : fw2;
  const float* b2 = blockIdx.y ? gb2 : fb2;
  float* out = blockIdx.y ? tg : tf;
  int t = threadIdx.x;
  int c = t & 127, kh = t >> 7;
  int o = t & 63, kh2 = t >> 6;
  float rw1[64];
#pragma unroll
  for (int i = 0; i < 64; i++) rw1[i] = w1[(kh*64 + i)*128 + c];
  float rw2[32];
#pragma unroll
  for (int i = 0; i < 32; i++) rw2[i] = w2[(kh2*32 + i)*64 + o];
  float bb1 = b1[c], bb2 = b2[o];
  __shared__ float erow[4][128];
  __shared__ float hidp[2][4][128];
  __shared__ float hid[4][128];
  __shared__ float outp[4][4][64];
  int r0 = blockIdx.x*32;
  for (int it = 0; it < 8; it++){
    int rbase = r0 + it*4;
    ((float2*)erow)[t] = ((const float2*)(embed + (size_t)rbase*128))[t];
    __syncthreads();
#pragma unroll
    for (int g = 0; g < 4; g++){
      float s = 0.f;
#pragma unroll
      for (int i = 0; i < 64; i++) s += erow[g][kh*64 + i]*rw1[i];
      hidp[kh][g][c] = s;
    }
    __syncthreads();
#pragma unroll
    for (int gg = 0; gg < 2; gg++){
      int g = kh + 2*gg;
      hid[g][c] = eluf(bb1 + hidp[0][g][c] + hidp[1][g][c]);
    }
    __syncthreads();
#pragma unroll
    for (int g = 0; g < 4; g++){
      float s = 0.f;
#pragma unroll
      for (int i = 0; i < 32; i++) s += hid[g][kh2*32 + i]*rw2[i];
      outp[kh2][g][o] = s;
    }
    __syncthreads();
    { int g = t >> 6;
      out[(size_t)(rbase + g)*64 + o] =
        eluf(bb2 + outp[0][g][o] + outp[1][g][o] + outp[2][g][o] + outp[3][g][o]); }
    __syncthreads();
  }
}

// ---------------- E4: pred = rowwise dot of gathered tf/tg (float4, 16 lanes/pair) ----------------
__global__ __launch_bounds__(256) void k_pred(
    const int* __restrict__ ts, const float4* __restrict__ tf4,
    const float4* __restrict__ tg4, float* __restrict__ out){
  int p = blockIdx.x*16 + (threadIdx.x >> 4);
  int l = threadIdx.x & 15;
  int i = ts[2*p], j = ts[2*p + 1];
  float4 a = tf4[(size_t)i*16 + l], b = tg4[(size_t)j*16 + l];
  float v = a.x*b.x + a.y*b.y + a.z*b.z + a.w*b.w;
  v += __shfl_xor(v, 1); v += __shfl_xor(v, 2);
  v += __shfl_xor(v, 4); v += __shfl_xor(v, 8);
  if (l == 0) out[p] = v;
}

// ---------------- workspace layout ----------------
#define OFF_MASK  ((size_t)0)
#define OFF_X16   ((size_t)8388608)
#define OFF_WT16  ((size_t)20971520)
#define OFF_HT16  ((size_t)21757952)
#define OFF_WH1   ((size_t)30146560)
#define OFF_WH2   ((size_t)30212096)
#define OFF_C1    ((size_t)30277632)
#define OFF_C2    ((size_t)30343168)
#define OFF_GMAX  ((size_t)30408704)
#define OFF_NUM1  ((size_t)30408960)
#define OFF_DEN1  ((size_t)47186176)
#define OFF_GT16  ((size_t)47251712)
#define OFF_WC1L  ((size_t)49348864)
#define OFF_WC2L  ((size_t)49381632)
#define OFF_NUMC  ((size_t)49414400)
#define OFF_DENC  ((size_t)53608704)
#define OFF_EMB   ((size_t)53641472)
#define OFF_TF    ((size_t)57835776)
#define OFF_TG    ((size_t)59932928)

extern "C" void kernel_launch(void* const* d_in, const int* in_sizes, int n_in,
                              void* d_out, int out_size, void* d_ws, size_t ws_size,
                              hipStream_t stream){
  const float* x      = (const float*)d_in[0];
  const int*   adj    = (const int*)d_in[1];
  const int*   ts     = (const int*)d_in[2];
  const float* head_W = (const float*)d_in[3];
  const float* head_a = (const float*)d_in[4];
  const float* head_b = (const float*)d_in[5];
  const float* conv_w = (const float*)d_in[6];
  const float* conv_cb= (const float*)d_in[7];
  const float* conv_a = (const float*)d_in[8];
  const float* conv_b = (const float*)d_in[9];
  const float* tf_w1  = (const float*)d_in[10];
  const float* tf_b1  = (const float*)d_in[11];
  const float* tf_w2  = (const float*)d_in[12];
  const float* tf_b2  = (const float*)d_in[13];
  const float* tg_w1  = (const float*)d_in[14];
  const float* tg_b1  = (const float*)d_in[15];
  const float* tg_w2  = (const float*)d_in[16];
  const float* tg_b2  = (const float*)d_in[17];
  float* outp = (float*)d_out;
  char* ws = (char*)d_ws;

  unsigned* maskw = (unsigned*)(ws + OFF_MASK);
  f16*   x16   = (f16*)(ws + OFF_X16);
  f16*   Wt16  = (f16*)(ws + OFF_WT16);
  f16*   hT16  = (f16*)(ws + OFF_HT16);
  float* wh1   = (float*)(ws + OFF_WH1);
  float* wh2   = (float*)(ws + OFF_WH2);
  float* c1    = (float*)(ws + OFF_C1);
  unsigned* gmax = (unsigned*)(ws + OFF_GMAX);
  float* num1  = (float*)(ws + OFF_NUM1);
  float* den1  = (float*)(ws + OFF_DEN1);
  f16*   gT16  = (f16*)(ws + OFF_GT16);
  float* wc1L  = (float*)(ws + OFF_WC1L);
  float* wc2L  = (float*)(ws + OFF_WC2L);
  float* numc  = (float*)(ws + OFF_NUMC);
  float* denc  = (float*)(ws + OFF_DENC);
  float* emb   = (float*)(ws + OFF_EMB);
  float* tf    = (float*)(ws + OFF_TF);
  float* tg    = (float*)(ws + OFF_TG);

  // k_init replaces 4 hipMemsetAsync + k_pack + k_cast_x + k_wt (same bytes, one launch)
  k_init    <<<IB_TOT, 256, 0, stream>>>((const int4*)adj, maskw, x, x16, head_W, Wt16,
                                         wh1, gmax, num1, numc);
  k_gemm_h  <<<dim3(NN/64, DT/128), 256, 0, stream>>>(x16, Wt16, head_a, hT16, wh1, wh2);
  k_post    <<<(2*NN)/256, 256, 0, stream>>>(wh2, gmax, c1);
  k_agg_head<<<dim3(NN/64, JS1, 2), 256, 0, stream>>>(hT16, maskw, wh1, c1, gmax, num1, den1);
  k_merge_conv<<<NN/2, 256, 0, stream>>>(num1, den1, head_b, conv_w, conv_cb, conv_a, gT16, wc1L, wc2L);
  k_agg_conv<<<dim3(NN/64, 8), 256, 0, stream>>>(gT16, maskw, wc1L, wc2L, numc, denc);
  k_embed   <<<NN/2, 256, 0, stream>>>(numc, denc, conv_b, emb);
  k_mlp     <<<dim3(NN/32, 2), 256, 0, stream>>>(emb, tf_w1, tf_b1, tf_w2, tf_b2,
                                                 tg_w1, tg_b1, tg_w2, tg_b2, tf, tg);
  k_pred    <<<EPAIRS/16, 256, 0, stream>>>(ts, (const float4*)tf, (const float4*)tg, outp);
}

// Round 13
// 640.646 us; speedup vs baseline: 1.0801x; 1.0230x over previous
//
#include <hip/hip_runtime.h>

// GATCL: 2-head GAT (N=8192, D=256) + feature conv (K=129) + GAT(D=128) + 2 MLPs + pair dots.
// R15: R14 + k_embed folded into k_mlp (wave-per-row l2norm inline on numc/denc; both MLP
// branches recompute embed redundantly — deterministic, trivial VALU). 9 -> 8 dispatches,
// embed buffer round-trip eliminated. All other kernels R14 verbatim.

typedef _Float16 f16;
typedef _Float16 f16x8 __attribute__((ext_vector_type(8)));
typedef float f32x4 __attribute__((ext_vector_type(4)));

#define DEV __device__ __forceinline__
#define L2E 1.4426950408889634f
#define NN 8192
#define IND 768
#define D1 256
#define DT 512
#define D2 128
#define KC 129
#define EPAIRS 100000
#define JS1 4

#if __has_builtin(__builtin_amdgcn_exp2f)
#define EXP2(x) __builtin_amdgcn_exp2f(x)
#else
#define EXP2(x) exp2f(x)
#endif

DEV float eluf(float x){ return x > 0.f ? x : EXP2(x*L2E) - 1.f; }

// async 16B global->LDS (LDS dest is wave-uniform base; lane writes base+lane*16)
DEV void gload_lds16(const void* g, void* l){
  __builtin_amdgcn_global_load_lds(
      (const __attribute__((address_space(1))) unsigned*)g,
      (__attribute__((address_space(3))) unsigned*)l, 16, 0, 0);
}

// ---------------- INIT: pack | cast_x | wt | zero accumulators — one launch ----------------
#define IB_PACK  65536
#define IB_CAST  (IB_PACK + 6144)
#define IB_WT    (IB_CAST + 512)
#define IB_Z1    (IB_WT + 1028)
#define IB_Z2    (IB_Z1 + 258)
#define IB_TOT   (IB_Z2 + 8)
__global__ __launch_bounds__(256) void k_init(
    const int4* __restrict__ adj4, unsigned* __restrict__ maskw,
    const float* __restrict__ x, f16* __restrict__ x16,
    const float* __restrict__ W, f16* __restrict__ Wt,
    float* __restrict__ wh1, unsigned* __restrict__ gmax,
    float* __restrict__ num1, float* __restrict__ numc){
  int b = blockIdx.x, t = threadIdx.x;
  if (b < IB_PACK){                      // pack adjacency into bit mask
    int idx = b*256 + t;                 // int4 index; j-flat = 4*idx
    int4 v = adj4[idx];
    unsigned n = (unsigned)(v.x > 0) | ((unsigned)(v.y > 0) << 1)
               | ((unsigned)(v.z > 0) << 2) | ((unsigned)(v.w > 0) << 3);
    n |= __shfl_xor(n, 1) << 4;
    n |= __shfl_xor(n, 2) << 8;
    n |= __shfl_xor(n, 4) << 16;
    if ((t & 7) == 0) maskw[idx >> 3] = n;
  } else if (b < IB_CAST){               // cast x to fp16
    int i = ((b - IB_PACK)*256 + t)*4;
    float4 v = *(const float4*)(x + i);
    union { f16 h[4]; uint2 u; } p;
    p.h[0]=(f16)v.x; p.h[1]=(f16)v.y; p.h[2]=(f16)v.z; p.h[3]=(f16)v.w;
    *(uint2*)(x16 + i) = p.u;
  } else if (b < IB_WT){                 // Wt[n'=h*256+d][k] = W[h][k][d]
    int np = b - IB_CAST; int h = np >> 8, d = np & 255;
    for (int k = t; k < IND; k += 256)
      Wt[(size_t)np*IND + k] = (f16)W[((size_t)h*IND + k)*D1 + d];
  } else {                               // zero accumulators, 16 KB/block float4 stores
    char* p; int rb;
    if (b < IB_Z1){ p = (char*)num1; rb = b - IB_WT; }
    else if (b < IB_Z2){ p = (char*)numc; rb = b - IB_Z1; }
    else { p = (char*)wh1; rb = b - IB_Z2;
           if (rb == 0 && t == 0){ gmax[0] = 0u; gmax[1] = 0u; } }
    float4 z = {0.f, 0.f, 0.f, 0.f};
    float4* q = (float4*)(p + (size_t)rb*16384);
#pragma unroll
    for (int k2 = 0; k2 < 4; k2++) q[k2*256 + t] = z;
  }
}

// ---------------- G1: h = x @ W' (8192x512), BK=64, write hT fp16 + wh1/wh2 atomics ----------------
__global__ __launch_bounds__(256, 4) void k_gemm_h(
    const f16* __restrict__ x16, const f16* __restrict__ Wt,
    const float* __restrict__ head_a,
    f16* __restrict__ hT, float* __restrict__ wh1, float* __restrict__ wh2){
  __shared__ f16 As[64*64];      // linear, 16B-chunk swizzled within each 128B row
  __shared__ f16 Bs[128*64];     // linear, 16B-chunk swizzled
  int m0 = blockIdx.x*64, n0 = blockIdx.y*128;
  int t = threadIdx.x, lane = t & 63, w = t >> 6;
  int wi = w >> 1, wd = w & 1;
  int rm = lane & 15, qm = (lane >> 4)*8;
  const int wb = t & ~63;        // wave-uniform staging base index
  f32x4 acc[2][4] = {};
  for (int k0 = 0; k0 < IND; k0 += 64){
#pragma unroll
    for (int p = 0; p < 2; p++){
      int idx = p*256 + t;
      int dr = idx >> 3, gch = (idx & 7) ^ (dr & 7);
      gload_lds16(&x16[(size_t)(m0 + dr)*IND + k0 + gch*8], &As[(p*256 + wb)*8]);
    }
#pragma unroll
    for (int p = 0; p < 4; p++){
      int idx = p*256 + t;
      int dr = idx >> 3, gch = (idx & 7) ^ (dr & 7);
      gload_lds16(&Wt[(size_t)(n0 + dr)*IND + k0 + gch*8], &Bs[(p*256 + wb)*8]);
    }
    __syncthreads();
#pragma unroll
    for (int ks = 0; ks < 2; ks++){
      int sc = (ks*4 + (qm >> 3)) ^ (rm & 7);  // swizzled 16B-chunk within row
      f16x8 a0 = *(const f16x8*)&As[(wi*32 + rm)*64 + sc*8];
      f16x8 a1 = *(const f16x8*)&As[(wi*32 + 16 + rm)*64 + sc*8];
#pragma unroll
      for (int fn = 0; fn < 4; fn++){
        f16x8 b = *(const f16x8*)&Bs[(wd*64 + fn*16 + rm)*64 + sc*8];
        acc[0][fn] = __builtin_amdgcn_mfma_f32_16x16x32_f16(a0, b, acc[0][fn], 0, 0, 0);
        acc[1][fn] = __builtin_amdgcn_mfma_f32_16x16x32_f16(a1, b, acc[1][fn], 0, 0, 0);
      }
    }
    __syncthreads();
  }
  int quad = lane >> 4, cl = lane & 15;
  int head = n0 >> 8;
  float a1v[4], a2v[4];
#pragma unroll
  for (int fn = 0; fn < 4; fn++){
    int d = (n0 & 255) + wd*64 + fn*16 + cl;
    a1v[fn] = head_a[head*DT + d];
    a2v[fn] = head_a[head*DT + D1 + d];
  }
  float p1[2][4], p2[2][4];
#pragma unroll
  for (int fi = 0; fi < 2; fi++){
#pragma unroll
    for (int fn = 0; fn < 4; fn++){
      int npg = n0 + wd*64 + fn*16 + cl;
      int mg = m0 + wi*32 + fi*16 + quad*4;
      union { f16 h[4]; uint2 u; } pk;
#pragma unroll
      for (int reg = 0; reg < 4; reg++) pk.h[reg] = (f16)acc[fi][fn][reg];
      *(uint2*)&hT[(size_t)npg*NN + mg] = pk.u;
    }
#pragma unroll
    for (int reg = 0; reg < 4; reg++){
      float s1 = 0.f, s2 = 0.f;
#pragma unroll
      for (int fn = 0; fn < 4; fn++){ s1 += acc[fi][fn][reg]*a1v[fn]; s2 += acc[fi][fn][reg]*a2v[fn]; }
      p1[fi][reg] = s1; p2[fi][reg] = s2;
    }
  }
#pragma unroll
  for (int o = 1; o < 16; o <<= 1){
#pragma unroll
    for (int fi = 0; fi < 2; fi++)
#pragma unroll
      for (int reg = 0; reg < 4; reg++){
        p1[fi][reg] += __shfl_xor(p1[fi][reg], o);
        p2[fi][reg] += __shfl_xor(p2[fi][reg], o);
      }
  }
  if (cl == 0){
#pragma unroll
    for (int fi = 0; fi < 2; fi++)
#pragma unroll
      for (int reg = 0; reg < 4; reg++){
        int mg = m0 + wi*32 + fi*16 + quad*4 + reg;
        atomicAdd(&wh1[head*NN + mg], p1[fi][reg]);
        atomicAdd(&wh2[head*NN + mg], p2[fi][reg]);
      }
  }
}

// ---------------- P4: gmax | colterms fused (one wh2 pass) ----------------
__global__ __launch_bounds__(256) void k_post(const float* __restrict__ wh2,
                                              unsigned* __restrict__ gmax,
                                              float* __restrict__ c1){
  int i = blockIdx.x*256 + threadIdx.x;    // over 2*NN; waves never straddle heads
  float v = wh2[i];
  c1[i] = v*L2E;
  int h = i >> 13;                          // i / NN
  float m = v;
#pragma unroll
  for (int o = 32; o > 0; o >>= 1) m = fmaxf(m, __shfl_xor(m, o));
  if ((threadIdx.x & 63) == 0){
    unsigned b = __float_as_uint(m);
    unsigned enc = (b & 0x80000000u) ? ~b : (b | 0x80000000u);
    atomicMax(gmax + h, enc);
  }
}

// ---------------- A1: head GAT aggregation. i-tile 64, full D=256, j-split 4 ----------------
__global__ __launch_bounds__(256, 4) void k_agg_head(
    const f16* __restrict__ hT, const unsigned* __restrict__ maskw,
    const float* __restrict__ wh1, const float* __restrict__ c1,
    const unsigned* __restrict__ gmaxp,
    float* __restrict__ num, float* __restrict__ den){
  __shared__ f16 Hs[256*64];     // linear, 16B-chunk swizzled within each 128B row
  __shared__ f16 Ws[64*64];      // linear, 16B-chunk swizzled
  int head = blockIdx.z;
  int i0 = blockIdx.x*64;
  int jbase = blockIdx.y*(NN/JS1);
  const f16* hTh = hT + (size_t)head*D1*NN;
  int t = threadIdx.x, lane = t & 63, w = t >> 6;
  int rm = lane & 15, qm = (lane >> 4)*8;
  int si = t >> 2, sjq = (t & 3)*16;
  // per-row score terms (4 lanes per row; broadcast loads)
  unsigned e = gmaxp[head];
  float gmax = __uint_as_float((e & 0x80000000u) ? (e ^ 0x80000000u) : ~e);
  float u = wh1[head*NN + i0 + si];
  float sm = u + gmax;
  float M = (sm > 0.f ? sm : 0.2f*sm)*L2E;   // leaky(wh1+gmax) in log2 units
  float ra = u*L2E - M;                      // s1 = ra + c1[j]
  float rb = -0.8f*M;                        // s2 = 0.2*s1 + rb  (exact identity)
  const float* c1h = c1 + head*NN;
  const unsigned* mrowp = maskw + (size_t)(i0 + si)*(NN/32);
  float rden = 0.f;
  f32x4 acc[4][4] = {};
  const int wb = t & ~63;        // wave-uniform staging base index
  const int wsbase = si*64;
  const int wc0 = sjq >> 3;      // this thread's first 16B chunk in its Ws row
  for (int j0 = 0; j0 < NN/JS1; j0 += 64){
    int jg = jbase + j0;
    // stage Hs[d=256][j=64] via async DMA; per-lane global src picks chunk (c^(row&7))
#pragma unroll
    for (int p = 0; p < 8; p++){
      int idx = p*256 + t;
      int dr = idx >> 3, gch = (idx & 7) ^ (dr & 7);
      gload_lds16(hTh + (size_t)dr*NN + jg + gch*8, &Hs[(p*256 + wb)*8]);
    }
    // scores: streamed float4 reads (cache-resident), short live ranges
    unsigned mb = mrowp[(jg + sjq) >> 5] >> (sjq & 31);
    f16x8 wlo, whi;
    float dsum = 0.f;
#pragma unroll
    for (int k = 0; k < 4; k++){
      float4 va = *(const float4*)&c1h[jg + sjq + 4*k];
      float s0 = ra + va.x, s1 = ra + va.y, s2 = ra + va.z, s3 = ra + va.w;
      float w0 = EXP2(fmaxf(s0, fmaf(0.2f, s0, rb)));
      float w1 = EXP2(fmaxf(s1, fmaf(0.2f, s1, rb)));
      float w2 = EXP2(fmaxf(s2, fmaf(0.2f, s2, rb)));
      float w3 = EXP2(fmaxf(s3, fmaf(0.2f, s3, rb)));
      w0 = ((mb >> (4*k + 0)) & 1u) ? w0 : 0.f;
      w1 = ((mb >> (4*k + 1)) & 1u) ? w1 : 0.f;
      w2 = ((mb >> (4*k + 2)) & 1u) ? w2 : 0.f;
      w3 = ((mb >> (4*k + 3)) & 1u) ? w3 : 0.f;
      dsum += (w0 + w1) + (w2 + w3);
      if (k < 2){
        wlo[4*k]=(f16)w0; wlo[4*k+1]=(f16)w1; wlo[4*k+2]=(f16)w2; wlo[4*k+3]=(f16)w3;
      } else {
        whi[4*k-8]=(f16)w0; whi[4*k-7]=(f16)w1; whi[4*k-6]=(f16)w2; whi[4*k-5]=(f16)w3;
      }
    }
    *(f16x8*)&Ws[wsbase + ((wc0    ) ^ (si & 7))*8] = wlo;
    *(f16x8*)&Ws[wsbase + ((wc0 + 1) ^ (si & 7))*8] = whi;
    dsum += __shfl_xor(dsum, 1);
    dsum += __shfl_xor(dsum, 2);
    rden += dsum;
    __syncthreads();               // drains DMA (vmcnt) + Ws writes (lgkm)
    // MFMA: wave w owns d-range w*64..w*64+63, all 64 i
#pragma unroll
    for (int ks = 0; ks < 2; ks++){
      int sc = (ks*4 + (qm >> 3)) ^ (rm & 7);  // swizzled 16B-chunk within row
      f16x8 a[4], b[4];
#pragma unroll
      for (int mi = 0; mi < 4; mi++) a[mi] = *(const f16x8*)&Ws[(mi*16 + rm)*64 + sc*8];
#pragma unroll
      for (int fn = 0; fn < 4; fn++)
        b[fn] = *(const f16x8*)&Hs[(w*64 + fn*16 + rm)*64 + sc*8];
#pragma unroll
      for (int mi = 0; mi < 4; mi++)
#pragma unroll
        for (int fn = 0; fn < 4; fn++)
          acc[mi][fn] = __builtin_amdgcn_mfma_f32_16x16x32_f16(a[mi], b[fn], acc[mi][fn], 0, 0, 0);
    }
    __syncthreads();
  }
  if ((t & 3) == 0) atomicAdd(&den[head*NN + i0 + si], rden);
  int quad = lane >> 4, cl = lane & 15;
#pragma unroll
  for (int mi = 0; mi < 4; mi++)
#pragma unroll
    for (int fn = 0; fn < 4; fn++){
      int rr = i0 + mi*16 + quad*4;
      int dc = w*64 + fn*16 + cl;
#pragma unroll
      for (int reg = 0; reg < 4; reg++)
        atomicAdd(&num[((size_t)head*NN + rr + reg)*D1 + dc], acc[mi][fn][reg]);
    }
}

// ---------------- E1: merge heads -> z -> conv -> gT(fp16) + wc1L/wc2L ----------------
__global__ __launch_bounds__(256) void k_merge_conv(
    const float* __restrict__ num, const float* __restrict__ den,
    const float* __restrict__ head_b, const float* __restrict__ conv_w,
    const float* __restrict__ conv_cb, const float* __restrict__ conv_a,
    f16* __restrict__ gT, float* __restrict__ wc1L, float* __restrict__ wc2L){
  __shared__ float zrow[2][256];
  __shared__ float cw[KC];
  __shared__ float ca[256];
  __shared__ float red[2][2];
  __shared__ float red2[2][2][2];
  int t = threadIdx.x, g = t >> 7, c = t & 127;
  int r = blockIdx.x*2 + g;
  if (t < KC) cw[t] = conv_w[t];
  ca[t] = conv_a[t];
  float zv0 = 0.f, zv1 = 0.f;
#pragma unroll
  for (int h = 0; h < 2; h++){
    const float* nr = num + ((size_t)h*NN + r)*D1;
    float inv = 1.f / den[h*NN + r];
    float e0 = eluf(nr[c]*inv);
    float e1 = eluf(nr[c + 128]*inv);
    float ss = e0*e0 + e1*e1;
#pragma unroll
    for (int o = 32; o > 0; o >>= 1) ss += __shfl_xor(ss, o);
    if ((t & 63) == 0) red[g][(t >> 6) & 1] = ss;
    __syncthreads();
    float invn = 1.f / fmaxf(sqrtf(red[g][0] + red[g][1]), 1e-12f);
    zv0 += e0*invn + head_b[h*D1 + c];
    zv1 += e1*invn + head_b[h*D1 + 128 + c];
    __syncthreads();
  }
  zrow[g][c]       = eluf(0.5f*zv0);
  zrow[g][c + 128] = eluf(0.5f*zv1);
  __syncthreads();
  float s = conv_cb[0];
  for (int k = 0; k < KC; k++) s += zrow[g][c + k]*cw[k];
  gT[(size_t)c*NN + r] = (f16)s;
  float p1 = s*ca[c], p2 = s*ca[128 + c];
#pragma unroll
  for (int o = 32; o > 0; o >>= 1){ p1 += __shfl_xor(p1, o); p2 += __shfl_xor(p2, o); }
  if ((t & 63) == 0){ red2[g][(t >> 6) & 1][0] = p1; red2[g][(t >> 6) & 1][1] = p2; }
  __syncthreads();
  if ((t & 127) == 0){
    wc1L[r] = (red2[g][0][0] + red2[g][1][0])*L2E;
    wc2L[r] = (red2[g][0][1] + red2[g][1][1])*L2E;
  }
}

// ---------------- A2: conv GAT aggregation (elu scores, m=0). i-tile 64, D=128, j-split 8 ----------------
__global__ __launch_bounds__(256, 4) void k_agg_conv(
    const f16* __restrict__ gT, const unsigned* __restrict__ maskw,
    const float* __restrict__ wc1L, const float* __restrict__ wc2L,
    float* __restrict__ num, float* __restrict__ den){
  __shared__ f16 Hs[128*64];     // linear, chunk-swizzled
  __shared__ f16 Ws[64*64];      // linear, chunk-swizzled
  int i0 = blockIdx.x*64;
  int jbase = blockIdx.y*1024;
  int t = threadIdx.x, lane = t & 63, w = t >> 6;
  int rm = lane & 15, qm = (lane >> 4)*8;
  int si = t >> 2, sjq = (t & 3)*16;
  float ra = wc1L[i0 + si];
  const unsigned* mrowp = maskw + (size_t)(i0 + si)*(NN/32);
  float rden = 0.f;
  f32x4 acc[4][2] = {};
  const int wb = t & ~63;
  const int wsbase = si*64;
  const int wc0 = sjq >> 3;
  for (int j0 = 0; j0 < 1024; j0 += 64){
    int jg = jbase + j0;
#pragma unroll
    for (int p = 0; p < 4; p++){
      int idx = p*256 + t;
      int dr = idx >> 3, gch = (idx & 7) ^ (dr & 7);
      gload_lds16(gT + (size_t)dr*NN + jg + gch*8, &Hs[(p*256 + wb)*8]);
    }
    unsigned mb = mrowp[(jg + sjq) >> 5] >> (sjq & 31);
    f16x8 wlo, whi;
    float dsum = 0.f;
#pragma unroll
    for (int k = 0; k < 4; k++){
      float4 va = *(const float4*)&wc2L[jg + sjq + 4*k];
      float sL0 = ra + va.x, sL1 = ra + va.y, sL2 = ra + va.z, sL3 = ra + va.w;
      float t20 = EXP2(sL0), t21 = EXP2(sL1), t22 = EXP2(sL2), t23 = EXP2(sL3);
      float w0 = sL0 > 0.f ? t20 : EXP2((t20 - 1.f)*L2E);
      float w1 = sL1 > 0.f ? t21 : EXP2((t21 - 1.f)*L2E);
      float w2 = sL2 > 0.f ? t22 : EXP2((t22 - 1.f)*L2E);
      float w3 = sL3 > 0.f ? t23 : EXP2((t23 - 1.f)*L2E);
      w0 = ((mb >> (4*k + 0)) & 1u) ? w0 : 0.f;
      w1 = ((mb >> (4*k + 1)) & 1u) ? w1 : 0.f;
      w2 = ((mb >> (4*k + 2)) & 1u) ? w2 : 0.f;
      w3 = ((mb >> (4*k + 3)) & 1u) ? w3 : 0.f;
      dsum += (w0 + w1) + (w2 + w3);
      if (k < 2){
        wlo[4*k]=(f16)w0; wlo[4*k+1]=(f16)w1; wlo[4*k+2]=(f16)w2; wlo[4*k+3]=(f16)w3;
      } else {
        whi[4*k-8]=(f16)w0; whi[4*k-7]=(f16)w1; whi[4*k-6]=(f16)w2; whi[4*k-5]=(f16)w3;
      }
    }
    *(f16x8*)&Ws[wsbase + ((wc0    ) ^ (si & 7))*8] = wlo;
    *(f16x8*)&Ws[wsbase + ((wc0 + 1) ^ (si & 7))*8] = whi;
    dsum += __shfl_xor(dsum, 1);
    dsum += __shfl_xor(dsum, 2);
    rden += dsum;
    __syncthreads();
    // wave w owns d-range w*32..w*32+31, all 64 i
#pragma unroll
    for (int ks = 0; ks < 2; ks++){
      int sc = (ks*4 + (qm >> 3)) ^ (rm & 7);
      f16x8 a[4], b[2];
#pragma unroll
      for (int mi = 0; mi < 4; mi++) a[mi] = *(const f16x8*)&Ws[(mi*16 + rm)*64 + sc*8];
#pragma unroll
      for (int fn = 0; fn < 2; fn++)
        b[fn] = *(const f16x8*)&Hs[(w*32 + fn*16 + rm)*64 + sc*8];
#pragma unroll
      for (int mi = 0; mi < 4; mi++)
#pragma unroll
        for (int fn = 0; fn < 2; fn++)
          acc[mi][fn] = __builtin_amdgcn_mfma_f32_16x16x32_f16(a[mi], b[fn], acc[mi][fn], 0, 0, 0);
    }
    __syncthreads();
  }
  if ((t & 3) == 0) atomicAdd(&den[i0 + si], rden);
  int quad = lane >> 4, cl = lane & 15;
#pragma unroll
  for (int mi = 0; mi < 4; mi++)
#pragma unroll
    for (int fn = 0; fn < 2; fn++){
      int rr = i0 + mi*16 + quad*4;
      int dc = w*32 + fn*16 + cl;
#pragma unroll
      for (int reg = 0; reg < 4; reg++)
        atomicAdd(&num[(size_t)(rr + reg)*D2 + dc], acc[mi][fn][reg]);
    }
}

// ---------------- E3: embed (inline) + two 128->128->64 elu MLPs, 32 rows/block ----------------
// R15: embed = l2norm(elu(numc/denc)) + conv_b computed per-iter, wave g = row rbase+g
// (64 lanes x 2 elems, full-wave shfl reduce). Both blockIdx.y branches recompute identically.
__global__ __launch_bounds__(256) void k_mlp(
    const float* __restrict__ numc, const float* __restrict__ denc,
    const float* __restrict__ conv_b,
    const float* __restrict__ fw1, const float* __restrict__ fb1,
    const float* __restrict__ fw2, const float* __restrict__ fb2,
    const float* __restrict__ gw1, const float* __restrict__ gb1,
    const float* __restrict__ gw2, const float* __restrict__ gb2,
    float* __restrict__ tf, float* __restrict__ tg){
  const float* w1 = blockIdx.y ? gw1 : fw1;
  const float* b1 = blockIdx.y ? gb1 : fb1;
  const float* w2 = blockIdx.y ? gw2 : fw2;
  const float* b2 = blockIdx.y ? gb2 : fb2;
  float* out = blockIdx.y ? tg : tf;
  int t = threadIdx.x;
  int c = t & 127, kh = t >> 7;
  int o = t & 63, kh2 = t >> 6;
  int wv = t >> 6, ln = t & 63;        // wave = embed row within 4-row group
  float rw1[64];
#pragma unroll
  for (int i = 0; i < 64; i++) rw1[i] = w1[(kh*64 + i)*128 + c];
  float rw2[32];
#pragma unroll
  for (int i = 0; i < 32; i++) rw2[i] = w2[(kh2*32 + i)*64 + o];
  float bb1 = b1[c], bb2 = b2[o];
  float cb0 = conv_b[ln*2], cb1 = conv_b[ln*2 + 1];
  __shared__ float erow[4][128];
  __shared__ float hidp[2][4][128];
  __shared__ float hid[4][128];
  __shared__ float outp[4][4][64];
  int r0 = blockIdx.x*32;
  for (int it = 0; it < 8; it++){
    int rbase = r0 + it*4;
    // inline embed: wave wv handles row rbase+wv
    {
      float invd = 1.f / denc[rbase + wv];
      float2 nv = *(const float2*)(numc + (size_t)(rbase + wv)*D2 + ln*2);
      float e0 = eluf(nv.x*invd), e1 = eluf(nv.y*invd);
      float ss = e0*e0 + e1*e1;
#pragma unroll
      for (int oo = 32; oo > 0; oo >>= 1) ss += __shfl_xor(ss, oo);
      float invn = 1.f / fmaxf(sqrtf(ss), 1e-12f);
      erow[wv][ln*2]     = e0*invn + cb0;
      erow[wv][ln*2 + 1] = e1*invn + cb1;
    }
    __syncthreads();
#pragma unroll
    for (int g = 0; g < 4; g++){
      float s = 0.f;
#pragma unroll
      for (int i = 0; i < 64; i++) s += erow[g][kh*64 + i]*rw1[i];
      hidp[kh][g][c] = s;
    }
    __syncthreads();
#pragma unroll
    for (int gg = 0; gg < 2; gg++){
      int g = kh + 2*gg;
      hid[g][c] = eluf(bb1 + hidp[0][g][c] + hidp[1][g][c]);
    }
    __syncthreads();
#pragma unroll
    for (int g = 0; g < 4; g++){
      float s = 0.f;
#pragma unroll
      for (int i = 0; i < 32; i++) s += hid[g][kh2*32 + i]*rw2[i];
      outp[kh2][g][o] = s;
    }
    __syncthreads();
    { int g = t >> 6;
      out[(size_t)(rbase + g)*64 + o] =
        eluf(bb2 + outp[0][g][o] + outp[1][g][o] + outp[2][g][o] + outp[3][g][o]); }
    __syncthreads();
  }
}

// ---------------- E4: pred = rowwise dot of gathered tf/tg (float4, 16 lanes/pair) ----------------
__global__ __launch_bounds__(256) void k_pred(
    const int* __restrict__ ts, const float4* __restrict__ tf4,
    const float4* __restrict__ tg4, float* __restrict__ out){
  int p = blockIdx.x*16 + (threadIdx.x >> 4);
  int l = threadIdx.x & 15;
  int i = ts[2*p], j = ts[2*p + 1];
  float4 a = tf4[(size_t)i*16 + l], b = tg4[(size_t)j*16 + l];
  float v = a.x*b.x + a.y*b.y + a.z*b.z + a.w*b.w;
  v += __shfl_xor(v, 1); v += __shfl_xor(v, 2);
  v += __shfl_xor(v, 4); v += __shfl_xor(v, 8);
  if (l == 0) out[p] = v;
}

// ---------------- workspace layout ----------------
#define OFF_MASK  ((size_t)0)
#define OFF_X16   ((size_t)8388608)
#define OFF_WT16  ((size_t)20971520)
#define OFF_HT16  ((size_t)21757952)
#define OFF_WH1   ((size_t)30146560)
#define OFF_WH2   ((size_t)30212096)
#define OFF_C1    ((size_t)30277632)
#define OFF_GMAX  ((size_t)30408704)
#define OFF_NUM1  ((size_t)30408960)
#define OFF_DEN1  ((size_t)47186176)
#define OFF_GT16  ((size_t)47251712)
#define OFF_WC1L  ((size_t)49348864)
#define OFF_WC2L  ((size_t)49381632)
#define OFF_NUMC  ((size_t)49414400)
#define OFF_DENC  ((size_t)53608704)
#define OFF_TF    ((size_t)57835776)
#define OFF_TG    ((size_t)59932928)

extern "C" void kernel_launch(void* const* d_in, const int* in_sizes, int n_in,
                              void* d_out, int out_size, void* d_ws, size_t ws_size,
                              hipStream_t stream){
  const float* x      = (const float*)d_in[0];
  const int*   adj    = (const int*)d_in[1];
  const int*   ts     = (const int*)d_in[2];
  const float* head_W = (const float*)d_in[3];
  const float* head_a = (const float*)d_in[4];
  const float* head_b = (const float*)d_in[5];
  const float* conv_w = (const float*)d_in[6];
  const float* conv_cb= (const float*)d_in[7];
  const float* conv_a = (const float*)d_in[8];
  const float* conv_b = (const float*)d_in[9];
  const float* tf_w1  = (const float*)d_in[10];
  const float* tf_b1  = (const float*)d_in[11];
  const float* tf_w2  = (const float*)d_in[12];
  const float* tf_b2  = (const float*)d_in[13];
  const float* tg_w1  = (const float*)d_in[14];
  const float* tg_b1  = (const float*)d_in[15];
  const float* tg_w2  = (const float*)d_in[16];
  const float* tg_b2  = (const float*)d_in[17];
  float* outp = (float*)d_out;
  char* ws = (char*)d_ws;

  unsigned* maskw = (unsigned*)(ws + OFF_MASK);
  f16*   x16   = (f16*)(ws + OFF_X16);
  f16*   Wt16  = (f16*)(ws + OFF_WT16);
  f16*   hT16  = (f16*)(ws + OFF_HT16);
  float* wh1   = (float*)(ws + OFF_WH1);
  float* wh2   = (float*)(ws + OFF_WH2);
  float* c1    = (float*)(ws + OFF_C1);
  unsigned* gmax = (unsigned*)(ws + OFF_GMAX);
  float* num1  = (float*)(ws + OFF_NUM1);
  float* den1  = (float*)(ws + OFF_DEN1);
  f16*   gT16  = (f16*)(ws + OFF_GT16);
  float* wc1L  = (float*)(ws + OFF_WC1L);
  float* wc2L  = (float*)(ws + OFF_WC2L);
  float* numc  = (float*)(ws + OFF_NUMC);
  float* denc  = (float*)(ws + OFF_DENC);
  float* tf    = (float*)(ws + OFF_TF);
  float* tg    = (float*)(ws + OFF_TG);

  // k_init replaces 4 hipMemsetAsync + pack + cast_x + wt (same bytes, one launch)
  k_init    <<<IB_TOT, 256, 0, stream>>>((const int4*)adj, maskw, x, x16, head_W, Wt16,
                                         wh1, gmax, num1, numc);
  k_gemm_h  <<<dim3(NN/64, DT/128), 256, 0, stream>>>(x16, Wt16, head_a, hT16, wh1, wh2);
  k_post    <<<(2*NN)/256, 256, 0, stream>>>(wh2, gmax, c1);
  k_agg_head<<<dim3(NN/64, JS1, 2), 256, 0, stream>>>(hT16, maskw, wh1, c1, gmax, num1, den1);
  k_merge_conv<<<NN/2, 256, 0, stream>>>(num1, den1, head_b, conv_w, conv_cb, conv_a, gT16, wc1L, wc2L);
  k_agg_conv<<<dim3(NN/64, 8), 256, 0, stream>>>(gT16, maskw, wc1L, wc2L, numc, denc);
  k_mlp     <<<dim3(NN/32, 2), 256, 0, stream>>>(numc, denc, conv_b,
                                                 tf_w1, tf_b1, tf_w2, tf_b2,
                                                 tg_w1, tg_b1, tg_w2, tg_b2, tf, tg);
  k_pred    <<<EPAIRS/16, 256, 0, stream>>>(ts, (const float4*)tf, (const float4*)tg, outp);
}

// Round 15
// 637.773 us; speedup vs baseline: 1.0849x; 1.0045x over previous
//
#include <hip/hip_runtime.h>

// GATCL: 2-head GAT (N=8192, D=256) + feature conv (K=129) + GAT(D=128) + 2 MLPs + pair dots.
// R17 (= R16 resubmit; prior round failed on infra, diff is a pure blockIdx permutation):
// XCD-aware block mapping (T1) on both agg kernels. agg_head: 8 (j-quarter,head) sharing
// groups == 8 XCDs; slot = bid&7 picks the group so each XCD L2-caches exactly its 1MB hT
// panel (+c1 slice) instead of thrashing all 8. agg_conv: same with 8 j-eighths of gT.
// Pure permutation — no correctness dependence on the XCD mapping. Rest R15 verbatim.

typedef _Float16 f16;
typedef _Float16 f16x8 __attribute__((ext_vector_type(8)));
typedef float f32x4 __attribute__((ext_vector_type(4)));

#define DEV __device__ __forceinline__
#define L2E 1.4426950408889634f
#define NN 8192
#define IND 768
#define D1 256
#define DT 512
#define D2 128
#define KC 129
#define EPAIRS 100000
#define JS1 4

#if __has_builtin(__builtin_amdgcn_exp2f)
#define EXP2(x) __builtin_amdgcn_exp2f(x)
#else
#define EXP2(x) exp2f(x)
#endif

DEV float eluf(float x){ return x > 0.f ? x : EXP2(x*L2E) - 1.f; }

// async 16B global->LDS (LDS dest is wave-uniform base; lane writes base+lane*16)
DEV void gload_lds16(const void* g, void* l){
  __builtin_amdgcn_global_load_lds(
      (const __attribute__((address_space(1))) unsigned*)g,
      (__attribute__((address_space(3))) unsigned*)l, 16, 0, 0);
}

// ---------------- INIT: pack | cast_x | wt | zero accumulators — one launch ----------------
#define IB_PACK  65536
#define IB_CAST  (IB_PACK + 6144)
#define IB_WT    (IB_CAST + 512)
#define IB_Z1    (IB_WT + 1028)
#define IB_Z2    (IB_Z1 + 258)
#define IB_TOT   (IB_Z2 + 8)
__global__ __launch_bounds__(256) void k_init(
    const int4* __restrict__ adj4, unsigned* __restrict__ maskw,
    const float* __restrict__ x, f16* __restrict__ x16,
    const float* __restrict__ W, f16* __restrict__ Wt,
    float* __restrict__ wh1, unsigned* __restrict__ gmax,
    float* __restrict__ num1, float* __restrict__ numc){
  int b = blockIdx.x, t = threadIdx.x;
  if (b < IB_PACK){                      // pack adjacency into bit mask
    int idx = b*256 + t;                 // int4 index; j-flat = 4*idx
    int4 v = adj4[idx];
    unsigned n = (unsigned)(v.x > 0) | ((unsigned)(v.y > 0) << 1)
               | ((unsigned)(v.z > 0) << 2) | ((unsigned)(v.w > 0) << 3);
    n |= __shfl_xor(n, 1) << 4;
    n |= __shfl_xor(n, 2) << 8;
    n |= __shfl_xor(n, 4) << 16;
    if ((t & 7) == 0) maskw[idx >> 3] = n;
  } else if (b < IB_CAST){               // cast x to fp16
    int i = ((b - IB_PACK)*256 + t)*4;
    float4 v = *(const float4*)(x + i);
    union { f16 h[4]; uint2 u; } p;
    p.h[0]=(f16)v.x; p.h[1]=(f16)v.y; p.h[2]=(f16)v.z; p.h[3]=(f16)v.w;
    *(uint2*)(x16 + i) = p.u;
  } else if (b < IB_WT){                 // Wt[n'=h*256+d][k] = W[h][k][d]
    int np = b - IB_CAST; int h = np >> 8, d = np & 255;
    for (int k = t; k < IND; k += 256)
      Wt[(size_t)np*IND + k] = (f16)W[((size_t)h*IND + k)*D1 + d];
  } else {                               // zero accumulators, 16 KB/block float4 stores
    char* p; int rb;
    if (b < IB_Z1){ p = (char*)num1; rb = b - IB_WT; }
    else if (b < IB_Z2){ p = (char*)numc; rb = b - IB_Z1; }
    else { p = (char*)wh1; rb = b - IB_Z2;
           if (rb == 0 && t == 0){ gmax[0] = 0u; gmax[1] = 0u; } }
    float4 z = {0.f, 0.f, 0.f, 0.f};
    float4* q = (float4*)(p + (size_t)rb*16384);
#pragma unroll
    for (int k2 = 0; k2 < 4; k2++) q[k2*256 + t] = z;
  }
}

// ---------------- G1: h = x @ W' (8192x512), BK=64, write hT fp16 + wh1/wh2 atomics ----------------
__global__ __launch_bounds__(256, 4) void k_gemm_h(
    const f16* __restrict__ x16, const f16* __restrict__ Wt,
    const float* __restrict__ head_a,
    f16* __restrict__ hT, float* __restrict__ wh1, float* __restrict__ wh2){
  __shared__ f16 As[64*64];      // linear, 16B-chunk swizzled within each 128B row
  __shared__ f16 Bs[128*64];     // linear, 16B-chunk swizzled
  int m0 = blockIdx.x*64, n0 = blockIdx.y*128;
  int t = threadIdx.x, lane = t & 63, w = t >> 6;
  int wi = w >> 1, wd = w & 1;
  int rm = lane & 15, qm = (lane >> 4)*8;
  const int wb = t & ~63;        // wave-uniform staging base index
  f32x4 acc[2][4] = {};
  for (int k0 = 0; k0 < IND; k0 += 64){
#pragma unroll
    for (int p = 0; p < 2; p++){
      int idx = p*256 + t;
      int dr = idx >> 3, gch = (idx & 7) ^ (dr & 7);
      gload_lds16(&x16[(size_t)(m0 + dr)*IND + k0 + gch*8], &As[(p*256 + wb)*8]);
    }
#pragma unroll
    for (int p = 0; p < 4; p++){
      int idx = p*256 + t;
      int dr = idx >> 3, gch = (idx & 7) ^ (dr & 7);
      gload_lds16(&Wt[(size_t)(n0 + dr)*IND + k0 + gch*8], &Bs[(p*256 + wb)*8]);
    }
    __syncthreads();
#pragma unroll
    for (int ks = 0; ks < 2; ks++){
      int sc = (ks*4 + (qm >> 3)) ^ (rm & 7);  // swizzled 16B-chunk within row
      f16x8 a0 = *(const f16x8*)&As[(wi*32 + rm)*64 + sc*8];
      f16x8 a1 = *(const f16x8*)&As[(wi*32 + 16 + rm)*64 + sc*8];
#pragma unroll
      for (int fn = 0; fn < 4; fn++){
        f16x8 b = *(const f16x8*)&Bs[(wd*64 + fn*16 + rm)*64 + sc*8];
        acc[0][fn] = __builtin_amdgcn_mfma_f32_16x16x32_f16(a0, b, acc[0][fn], 0, 0, 0);
        acc[1][fn] = __builtin_amdgcn_mfma_f32_16x16x32_f16(a1, b, acc[1][fn], 0, 0, 0);
      }
    }
    __syncthreads();
  }
  int quad = lane >> 4, cl = lane & 15;
  int head = n0 >> 8;
  float a1v[4], a2v[4];
#pragma unroll
  for (int fn = 0; fn < 4; fn++){
    int d = (n0 & 255) + wd*64 + fn*16 + cl;
    a1v[fn] = head_a[head*DT + d];
    a2v[fn] = head_a[head*DT + D1 + d];
  }
  float p1[2][4], p2[2][4];
#pragma unroll
  for (int fi = 0; fi < 2; fi++){
#pragma unroll
    for (int fn = 0; fn < 4; fn++){
      int npg = n0 + wd*64 + fn*16 + cl;
      int mg = m0 + wi*32 + fi*16 + quad*4;
      union { f16 h[4]; uint2 u; } pk;
#pragma unroll
      for (int reg = 0; reg < 4; reg++) pk.h[reg] = (f16)acc[fi][fn][reg];
      *(uint2*)&hT[(size_t)npg*NN + mg] = pk.u;
    }
#pragma unroll
    for (int reg = 0; reg < 4; reg++){
      float s1 = 0.f, s2 = 0.f;
#pragma unroll
      for (int fn = 0; fn < 4; fn++){ s1 += acc[fi][fn][reg]*a1v[fn]; s2 += acc[fi][fn][reg]*a2v[fn]; }
      p1[fi][reg] = s1; p2[fi][reg] = s2;
    }
  }
#pragma unroll
  for (int o = 1; o < 16; o <<= 1){
#pragma unroll
    for (int fi = 0; fi < 2; fi++)
#pragma unroll
      for (int reg = 0; reg < 4; reg++){
        p1[fi][reg] += __shfl_xor(p1[fi][reg], o);
        p2[fi][reg] += __shfl_xor(p2[fi][reg], o);
      }
  }
  if (cl == 0){
#pragma unroll
    for (int fi = 0; fi < 2; fi++)
#pragma unroll
      for (int reg = 0; reg < 4; reg++){
        int mg = m0 + wi*32 + fi*16 + quad*4 + reg;
        atomicAdd(&wh1[head*NN + mg], p1[fi][reg]);
        atomicAdd(&wh2[head*NN + mg], p2[fi][reg]);
      }
  }
}

// ---------------- P4: gmax | colterms fused (one wh2 pass) ----------------
__global__ __launch_bounds__(256) void k_post(const float* __restrict__ wh2,
                                              unsigned* __restrict__ gmax,
                                              float* __restrict__ c1){
  int i = blockIdx.x*256 + threadIdx.x;    // over 2*NN; waves never straddle heads
  float v = wh2[i];
  c1[i] = v*L2E;
  int h = i >> 13;                          // i / NN
  float m = v;
#pragma unroll
  for (int o = 32; o > 0; o >>= 1) m = fmaxf(m, __shfl_xor(m, o));
  if ((threadIdx.x & 63) == 0){
    unsigned b = __float_as_uint(m);
    unsigned enc = (b & 0x80000000u) ? ~b : (b | 0x80000000u);
    atomicMax(gmax + h, enc);
  }
}

// ---------------- A1: head GAT aggregation. i-tile 64, full D=256, j-split 4 ----------------
// 1D grid 1024; slot = bid&7 -> (j-quarter, head) so each XCD (block i -> XCD i%8)
// hosts ONE sharing group and L2-caches its 1MB hT panel. i0 = (bid>>3)*64.
__global__ __launch_bounds__(256, 4) void k_agg_head(
    const f16* __restrict__ hT, const unsigned* __restrict__ maskw,
    const float* __restrict__ wh1, const float* __restrict__ c1,
    const unsigned* __restrict__ gmaxp,
    float* __restrict__ num, float* __restrict__ den){
  __shared__ f16 Hs[256*64];     // linear, 16B-chunk swizzled within each 128B row
  __shared__ f16 Ws[64*64];      // linear, 16B-chunk swizzled
  int bid = blockIdx.x;
  int slot = bid & 7;            // XCD slot = sharing group
  int head = slot & 1;
  int jbase = (slot >> 1)*(NN/JS1);
  int i0 = (bid >> 3)*64;
  const f16* hTh = hT + (size_t)head*D1*NN;
  int t = threadIdx.x, lane = t & 63, w = t >> 6;
  int rm = lane & 15, qm = (lane >> 4)*8;
  int si = t >> 2, sjq = (t & 3)*16;
  // per-row score terms (4 lanes per row; broadcast loads)
  unsigned e = gmaxp[head];
  float gmax = __uint_as_float((e & 0x80000000u) ? (e ^ 0x80000000u) : ~e);
  float u = wh1[head*NN + i0 + si];
  float sm = u + gmax;
  float M = (sm > 0.f ? sm : 0.2f*sm)*L2E;   // leaky(wh1+gmax) in log2 units
  float ra = u*L2E - M;                      // s1 = ra + c1[j]
  float rb = -0.8f*M;                        // s2 = 0.2*s1 + rb  (exact identity)
  const float* c1h = c1 + head*NN;
  const unsigned* mrowp = maskw + (size_t)(i0 + si)*(NN/32);
  float rden = 0.f;
  f32x4 acc[4][4] = {};
  const int wb = t & ~63;        // wave-uniform staging base index
  const int wsbase = si*64;
  const int wc0 = sjq >> 3;      // this thread's first 16B chunk in its Ws row
  for (int j0 = 0; j0 < NN/JS1; j0 += 64){
    int jg = jbase + j0;
    // stage Hs[d=256][j=64] via async DMA; per-lane global src picks chunk (c^(row&7))
#pragma unroll
    for (int p = 0; p < 8; p++){
      int idx = p*256 + t;
      int dr = idx >> 3, gch = (idx & 7) ^ (dr & 7);
      gload_lds16(hTh + (size_t)dr*NN + jg + gch*8, &Hs[(p*256 + wb)*8]);
    }
    // scores: streamed float4 reads (cache-resident), short live ranges
    unsigned mb = mrowp[(jg + sjq) >> 5] >> (sjq & 31);
    f16x8 wlo, whi;
    float dsum = 0.f;
#pragma unroll
    for (int k = 0; k < 4; k++){
      float4 va = *(const float4*)&c1h[jg + sjq + 4*k];
      float s0 = ra + va.x, s1 = ra + va.y, s2 = ra + va.z, s3 = ra + va.w;
      float w0 = EXP2(fmaxf(s0, fmaf(0.2f, s0, rb)));
      float w1 = EXP2(fmaxf(s1, fmaf(0.2f, s1, rb)));
      float w2 = EXP2(fmaxf(s2, fmaf(0.2f, s2, rb)));
      float w3 = EXP2(fmaxf(s3, fmaf(0.2f, s3, rb)));
      w0 = ((mb >> (4*k + 0)) & 1u) ? w0 : 0.f;
      w1 = ((mb >> (4*k + 1)) & 1u) ? w1 : 0.f;
      w2 = ((mb >> (4*k + 2)) & 1u) ? w2 : 0.f;
      w3 = ((mb >> (4*k + 3)) & 1u) ? w3 : 0.f;
      dsum += (w0 + w1) + (w2 + w3);
      if (k < 2){
        wlo[4*k]=(f16)w0; wlo[4*k+1]=(f16)w1; wlo[4*k+2]=(f16)w2; wlo[4*k+3]=(f16)w3;
      } else {
        whi[4*k-8]=(f16)w0; whi[4*k-7]=(f16)w1; whi[4*k-6]=(f16)w2; whi[4*k-5]=(f16)w3;
      }
    }
    *(f16x8*)&Ws[wsbase + ((wc0    ) ^ (si & 7))*8] = wlo;
    *(f16x8*)&Ws[wsbase + ((wc0 + 1) ^ (si & 7))*8] = whi;
    dsum += __shfl_xor(dsum, 1);
    dsum += __shfl_xor(dsum, 2);
    rden += dsum;
    __syncthreads();               // drains DMA (vmcnt) + Ws writes (lgkm)
    // MFMA: wave w owns d-range w*64..w*64+63, all 64 i
#pragma unroll
    for (int ks = 0; ks < 2; ks++){
      int sc = (ks*4 + (qm >> 3)) ^ (rm & 7);  // swizzled 16B-chunk within row
      f16x8 a[4], b[4];
#pragma unroll
      for (int mi = 0; mi < 4; mi++) a[mi] = *(const f16x8*)&Ws[(mi*16 + rm)*64 + sc*8];
#pragma unroll
      for (int fn = 0; fn < 4; fn++)
        b[fn] = *(const f16x8*)&Hs[(w*64 + fn*16 + rm)*64 + sc*8];
#pragma unroll
      for (int mi = 0; mi < 4; mi++)
#pragma unroll
        for (int fn = 0; fn < 4; fn++)
          acc[mi][fn] = __builtin_amdgcn_mfma_f32_16x16x32_f16(a[mi], b[fn], acc[mi][fn], 0, 0, 0);
    }
    __syncthreads();
  }
  if ((t & 3) == 0) atomicAdd(&den[head*NN + i0 + si], rden);
  int quad = lane >> 4, cl = lane & 15;
#pragma unroll
  for (int mi = 0; mi < 4; mi++)
#pragma unroll
    for (int fn = 0; fn < 4; fn++){
      int rr = i0 + mi*16 + quad*4;
      int dc = w*64 + fn*16 + cl;
#pragma unroll
      for (int reg = 0; reg < 4; reg++)
        atomicAdd(&num[((size_t)head*NN + rr + reg)*D1 + dc], acc[mi][fn][reg]);
    }
}

// ---------------- E1: merge heads -> z -> conv -> gT(fp16) + wc1L/wc2L ----------------
__global__ __launch_bounds__(256) void k_merge_conv(
    const float* __restrict__ num, const float* __restrict__ den,
    const float* __restrict__ head_b, const float* __restrict__ conv_w,
    const float* __restrict__ conv_cb, const float* __restrict__ conv_a,
    f16* __restrict__ gT, float* __restrict__ wc1L, float* __restrict__ wc2L){
  __shared__ float zrow[2][256];
  __shared__ float cw[KC];
  __shared__ float ca[256];
  __shared__ float red[2][2];
  __shared__ float red2[2][2][2];
  int t = threadIdx.x, g = t >> 7, c = t & 127;
  int r = blockIdx.x*2 + g;
  if (t < KC) cw[t] = conv_w[t];
  ca[t] = conv_a[t];
  float zv0 = 0.f, zv1 = 0.f;
#pragma unroll
  for (int h = 0; h < 2; h++){
    const float* nr = num + ((size_t)h*NN + r)*D1;
    float inv = 1.f / den[h*NN + r];
    float e0 = eluf(nr[c]*inv);
    float e1 = eluf(nr[c + 128]*inv);
    float ss = e0*e0 + e1*e1;
#pragma unroll
    for (int o = 32; o > 0; o >>= 1) ss += __shfl_xor(ss, o);
    if ((t & 63) == 0) red[g][(t >> 6) & 1] = ss;
    __syncthreads();
    float invn = 1.f / fmaxf(sqrtf(red[g][0] + red[g][1]), 1e-12f);
    zv0 += e0*invn + head_b[h*D1 + c];
    zv1 += e1*invn + head_b[h*D1 + 128 + c];
    __syncthreads();
  }
  zrow[g][c]       = eluf(0.5f*zv0);
  zrow[g][c + 128] = eluf(0.5f*zv1);
  __syncthreads();
  float s = conv_cb[0];
  for (int k = 0; k < KC; k++) s += zrow[g][c + k]*cw[k];
  gT[(size_t)c*NN + r] = (f16)s;
  float p1 = s*ca[c], p2 = s*ca[128 + c];
#pragma unroll
  for (int o = 32; o > 0; o >>= 1){ p1 += __shfl_xor(p1, o); p2 += __shfl_xor(p2, o); }
  if ((t & 63) == 0){ red2[g][(t >> 6) & 1][0] = p1; red2[g][(t >> 6) & 1][1] = p2; }
  __syncthreads();
  if ((t & 127) == 0){
    wc1L[r] = (red2[g][0][0] + red2[g][1][0])*L2E;
    wc2L[r] = (red2[g][0][1] + red2[g][1][1])*L2E;
  }
}

// ---------------- A2: conv GAT aggregation (elu scores, m=0). i-tile 64, D=128, j-split 8 ----------------
// 1D grid 1024; slot = bid&7 -> j-eighth so each XCD caches its 256KB gT panel.
__global__ __launch_bounds__(256, 4) void k_agg_conv(
    const f16* __restrict__ gT, const unsigned* __restrict__ maskw,
    const float* __restrict__ wc1L, const float* __restrict__ wc2L,
    float* __restrict__ num, float* __restrict__ den){
  __shared__ f16 Hs[128*64];     // linear, chunk-swizzled
  __shared__ f16 Ws[64*64];      // linear, chunk-swizzled
  int bid = blockIdx.x;
  int jbase = (bid & 7)*1024;
  int i0 = (bid >> 3)*64;
  int t = threadIdx.x, lane = t & 63, w = t >> 6;
  int rm = lane & 15, qm = (lane >> 4)*8;
  int si = t >> 2, sjq = (t & 3)*16;
  float ra = wc1L[i0 + si];
  const unsigned* mrowp = maskw + (size_t)(i0 + si)*(NN/32);
  float rden = 0.f;
  f32x4 acc[4][2] = {};
  const int wb = t & ~63;
  const int wsbase = si*64;
  const int wc0 = sjq >> 3;
  for (int j0 = 0; j0 < 1024; j0 += 64){
    int jg = jbase + j0;
#pragma unroll
    for (int p = 0; p < 4; p++){
      int idx = p*256 + t;
      int dr = idx >> 3, gch = (idx & 7) ^ (dr & 7);
      gload_lds16(gT + (size_t)dr*NN + jg + gch*8, &Hs[(p*256 + wb)*8]);
    }
    unsigned mb = mrowp[(jg + sjq) >> 5] >> (sjq & 31);
    f16x8 wlo, whi;
    float dsum = 0.f;
#pragma unroll
    for (int k = 0; k < 4; k++){
      float4 va = *(const float4*)&wc2L[jg + sjq + 4*k];
      float sL0 = ra + va.x, sL1 = ra + va.y, sL2 = ra + va.z, sL3 = ra + va.w;
      float t20 = EXP2(sL0), t21 = EXP2(sL1), t22 = EXP2(sL2), t23 = EXP2(sL3);
      float w0 = sL0 > 0.f ? t20 : EXP2((t20 - 1.f)*L2E);
      float w1 = sL1 > 0.f ? t21 : EXP2((t21 - 1.f)*L2E);
      float w2 = sL2 > 0.f ? t22 : EXP2((t22 - 1.f)*L2E);
      float w3 = sL3 > 0.f ? t23 : EXP2((t23 - 1.f)*L2E);
      w0 = ((mb >> (4*k + 0)) & 1u) ? w0 : 0.f;
      w1 = ((mb >> (4*k + 1)) & 1u) ? w1 : 0.f;
      w2 = ((mb >> (4*k + 2)) & 1u) ? w2 : 0.f;
      w3 = ((mb >> (4*k + 3)) & 1u) ? w3 : 0.f;
      dsum += (w0 + w1) + (w2 + w3);
      if (k < 2){
        wlo[4*k]=(f16)w0; wlo[4*k+1]=(f16)w1; wlo[4*k+2]=(f16)w2; wlo[4*k+3]=(f16)w3;
      } else {
        whi[4*k-8]=(f16)w0; whi[4*k-7]=(f16)w1; whi[4*k-6]=(f16)w2; whi[4*k-5]=(f16)w3;
      }
    }
    *(f16x8*)&Ws[wsbase + ((wc0    ) ^ (si & 7))*8] = wlo;
    *(f16x8*)&Ws[wsbase + ((wc0 + 1) ^ (si & 7))*8] = whi;
    dsum += __shfl_xor(dsum, 1);
    dsum += __shfl_xor(dsum, 2);
    rden += dsum;
    __syncthreads();
    // wave w owns d-range w*32..w*32+31, all 64 i
#pragma unroll
    for (int ks = 0; ks < 2; ks++){
      int sc = (ks*4 + (qm >> 3)) ^ (rm & 7);
      f16x8 a[4], b[2];
#pragma unroll
      for (int mi = 0; mi < 4; mi++) a[mi] = *(const f16x8*)&Ws[(mi*16 + rm)*64 + sc*8];
#pragma unroll
      for (int fn = 0; fn < 2; fn++)
        b[fn] = *(const f16x8*)&Hs[(w*32 + fn*16 + rm)*64 + sc*8];
#pragma unroll
      for (int mi = 0; mi < 4; mi++)
#pragma unroll
        for (int fn = 0; fn < 2; fn++)
          acc[mi][fn] = __builtin_amdgcn_mfma_f32_16x16x32_f16(a[mi], b[fn], acc[mi][fn], 0, 0, 0);
    }
    __syncthreads();
  }
  if ((t & 3) == 0) atomicAdd(&den[i0 + si], rden);
  int quad = lane >> 4, cl = lane & 15;
#pragma unroll
  for (int mi = 0; mi < 4; mi++)
#pragma unroll
    for (int fn = 0; fn < 2; fn++){
      int rr = i0 + mi*16 + quad*4;
      int dc = w*32 + fn*16 + cl;
#pragma unroll
      for (int reg = 0; reg < 4; reg++)
        atomicAdd(&num[(size_t)(rr + reg)*D2 + dc], acc[mi][fn][reg]);
    }
}

// ---------------- E3: embed (inline) + two 128->128->64 elu MLPs, 32 rows/block ----------------
__global__ __launch_bounds__(256) void k_mlp(
    const float* __restrict__ numc, const float* __restrict__ denc,
    const float* __restrict__ conv_b,
    const float* __restrict__ fw1, const float* __restrict__ fb1,
    const float* __restrict__ fw2, const float* __restrict__ fb2,
    const float* __restrict__ gw1, const float* __restrict__ gb1,
    const float* __restrict__ gw2, const float* __restrict__ gb2,
    float* __restrict__ tf, float* __restrict__ tg){
  const float* w1 = blockIdx.y ? gw1 : fw1;
  const float* b1 = blockIdx.y ? gb1 : fb1;
  const float* w2 = blockIdx.y ? gw2 : fw2;
  const float* b2 = blockIdx.y ? gb2 : fb2;
  float* out = blockIdx.y ? tg : tf;
  int t = threadIdx.x;
  int c = t & 127, kh = t >> 7;
  int o = t & 63, kh2 = t >> 6;
  int wv = t >> 6, ln = t & 63;        // wave = embed row within 4-row group
  float rw1[64];
#pragma unroll
  for (int i = 0; i < 64; i++) rw1[i] = w1[(kh*64 + i)*128 + c];
  float rw2[32];
#pragma unroll
  for (int i = 0; i < 32; i++) rw2[i] = w2[(kh2*32 + i)*64 + o];
  float bb1 = b1[c], bb2 = b2[o];
  float cb0 = conv_b[ln*2], cb1 = conv_b[ln*2 + 1];
  __shared__ float erow[4][128];
  __shared__ float hidp[2][4][128];
  __shared__ float hid[4][128];
  __shared__ float outp[4][4][64];
  int r0 = blockIdx.x*32;
  for (int it = 0; it < 8; it++){
    int rbase = r0 + it*4;
    // inline embed: wave wv handles row rbase+wv
    {
      float invd = 1.f / denc[rbase + wv];
      float2 nv = *(const float2*)(numc + (size_t)(rbase + wv)*D2 + ln*2);
      float e0 = eluf(nv.x*invd), e1 = eluf(nv.y*invd);
      float ss = e0*e0 + e1*e1;
#pragma unroll
      for (int oo = 32; oo > 0; oo >>= 1) ss += __shfl_xor(ss, oo);
      float invn = 1.f / fmaxf(sqrtf(ss), 1e-12f);
      erow[wv][ln*2]     = e0*invn + cb0;
      erow[wv][ln*2 + 1] = e1*invn + cb1;
    }
    __syncthreads();
#pragma unroll
    for (int g = 0; g < 4; g++){
      float s = 0.f;
#pragma unroll
      for (int i = 0; i < 64; i++) s += erow[g][kh*64 + i]*rw1[i];
      hidp[kh][g][c] = s;
    }
    __syncthreads();
#pragma unroll
    for (int gg = 0; gg < 2; gg++){
      int g = kh + 2*gg;
      hid[g][c] = eluf(bb1 + hidp[0][g][c] + hidp[1][g][c]);
    }
    __syncthreads();
#pragma unroll
    for (int g = 0; g < 4; g++){
      float s = 0.f;
#pragma unroll
      for (int i = 0; i < 32; i++) s += hid[g][kh2*32 + i]*rw2[i];
      outp[kh2][g][o] = s;
    }
    __syncthreads();
    { int g = t >> 6;
      out[(size_t)(rbase + g)*64 + o] =
        eluf(bb2 + outp[0][g][o] + outp[1][g][o] + outp[2][g][o] + outp[3][g][o]); }
    __syncthreads();
  }
}

// ---------------- E4: pred = rowwise dot of gathered tf/tg (float4, 16 lanes/pair) ----------------
__global__ __launch_bounds__(256) void k_pred(
    const int* __restrict__ ts, const float4* __restrict__ tf4,
    const float4* __restrict__ tg4, float* __restrict__ out){
  int p = blockIdx.x*16 + (threadIdx.x >> 4);
  int l = threadIdx.x & 15;
  int i = ts[2*p], j = ts[2*p + 1];
  float4 a = tf4[(size_t)i*16 + l], b = tg4[(size_t)j*16 + l];
  float v = a.x*b.x + a.y*b.y + a.z*b.z + a.w*b.w;
  v += __shfl_xor(v, 1); v += __shfl_xor(v, 2);
  v += __shfl_xor(v, 4); v += __shfl_xor(v, 8);
  if (l == 0) out[p] = v;
}

// ---------------- workspace layout ----------------
#define OFF_MASK  ((size_t)0)
#define OFF_X16   ((size_t)8388608)
#define OFF_WT16  ((size_t)20971520)
#define OFF_HT16  ((size_t)21757952)
#define OFF_WH1   ((size_t)30146560)
#define OFF_WH2   ((size_t)30212096)
#define OFF_C1    ((size_t)30277632)
#define OFF_GMAX  ((size_t)30408704)
#define OFF_NUM1  ((size_t)30408960)
#define OFF_DEN1  ((size_t)47186176)
#define OFF_GT16  ((size_t)47251712)
#define OFF_WC1L  ((size_t)49348864)
#define OFF_WC2L  ((size_t)49381632)
#define OFF_NUMC  ((size_t)49414400)
#define OFF_DENC  ((size_t)53608704)
#define OFF_TF    ((size_t)57835776)
#define OFF_TG    ((size_t)59932928)

extern "C" void kernel_launch(void* const* d_in, const int* in_sizes, int n_in,
                              void* d_out, int out_size, void* d_ws, size_t ws_size,
                              hipStream_t stream){
  const float* x      = (const float*)d_in[0];
  const int*   adj    = (const int*)d_in[1];
  const int*   ts     = (const int*)d_in[2];
  const float* head_W = (const float*)d_in[3];
  const float* head_a = (const float*)d_in[4];
  const float* head_b = (const float*)d_in[5];
  const float* conv_w = (const float*)d_in[6];
  const float* conv_cb= (const float*)d_in[7];
  const float* conv_a = (const float*)d_in[8];
  const float* conv_b = (const float*)d_in[9];
  const float* tf_w1  = (const float*)d_in[10];
  const float* tf_b1  = (const float*)d_in[11];
  const float* tf_w2  = (const float*)d_in[12];
  const float* tf_b2  = (const float*)d_in[13];
  const float* tg_w1  = (const float*)d_in[14];
  const float* tg_b1  = (const float*)d_in[15];
  const float* tg_w2  = (const float*)d_in[16];
  const float* tg_b2  = (const float*)d_in[17];
  float* outp = (float*)d_out;
  char* ws = (char*)d_ws;

  unsigned* maskw = (unsigned*)(ws + OFF_MASK);
  f16*   x16   = (f16*)(ws + OFF_X16);
  f16*   Wt16  = (f16*)(ws + OFF_WT16);
  f16*   hT16  = (f16*)(ws + OFF_HT16);
  float* wh1   = (float*)(ws + OFF_WH1);
  float* wh2   = (float*)(ws + OFF_WH2);
  float* c1    = (float*)(ws + OFF_C1);
  unsigned* gmax = (unsigned*)(ws + OFF_GMAX);
  float* num1  = (float*)(ws + OFF_NUM1);
  float* den1  = (float*)(ws + OFF_DEN1);
  f16*   gT16  = (f16*)(ws + OFF_GT16);
  float* wc1L  = (float*)(ws + OFF_WC1L);
  float* wc2L  = (float*)(ws + OFF_WC2L);
  float* numc  = (float*)(ws + OFF_NUMC);
  float* denc  = (float*)(ws + OFF_DENC);
  float* tf    = (float*)(ws + OFF_TF);
  float* tg    = (float*)(ws + OFF_TG);

  k_init    <<<IB_TOT, 256, 0, stream>>>((const int4*)adj, maskw, x, x16, head_W, Wt16,
                                         wh1, gmax, num1, numc);
  k_gemm_h  <<<dim3(NN/64, DT/128), 256, 0, stream>>>(x16, Wt16, head_a, hT16, wh1, wh2);
  k_post    <<<(2*NN)/256, 256, 0, stream>>>(wh2, gmax, c1);
  k_agg_head<<<NN/64*JS1*2, 256, 0, stream>>>(hT16, maskw, wh1, c1, gmax, num1, den1);
  k_merge_conv<<<NN/2, 256, 0, stream>>>(num1, den1, head_b, conv_w, conv_cb, conv_a, gT16, wc1L, wc2L);
  k_agg_conv<<<NN/64*8, 256, 0, stream>>>(gT16, maskw, wc1L, wc2L, numc, denc);
  k_mlp     <<<dim3(NN/32, 2), 256, 0, stream>>>(numc, denc, conv_b,
                                                 tf_w1, tf_b1, tf_w2, tf_b2,
                                                 tg_w1, tg_b1, tg_w2, tg_b2, tf, tg);
  k_pred    <<<EPAIRS/16, 256, 0, stream>>>(ts, (const float4*)tf, (const float4*)tg, outp);
}